// Round 11
// baseline (3850.246 us; speedup 1.0000x reference)
//
#include <hip/hip_runtime.h>
#include <hip/hip_bf16.h>
#include <math.h>

// HEAT layer. Round 10 (resubmit): CSR build via dst-range bucketing (phase A,
// ballot-segmented coalesced staging) + XCD-pinned hist/scatter (phase B) — kills
// the 154MB random line-write amplification. edge_agg3 / MFMA GEMMs unchanged.

#define NDIM 128
#define SCH 2048
#define MAXNB 64
#define NRNG 8

typedef __attribute__((ext_vector_type(8))) short short8;
typedef __attribute__((ext_vector_type(4))) float f32x4;

__device__ __forceinline__ float bf2f(unsigned short u) {
    union { unsigned int i; float f; } x; x.i = ((unsigned int)u) << 16; return x.f;
}
__device__ __forceinline__ unsigned short f2bf(float f) {
    unsigned int u = __float_as_uint(f);
    unsigned int r = (u + 0x7FFFu + ((u >> 16) & 1u)) >> 16;   // RNE
    return (unsigned short)r;
}

// ---------------- weight prep: 8 mats f32[k][n] -> bf16 [n][k] ----------------
__global__ void wt_prep(const float* __restrict__ Kw, const float* __restrict__ Qw,
                        const float* __restrict__ Vw, const float* __restrict__ Aw,
                        unsigned short* __restrict__ Wtbuf)
{
    const int b = blockIdx.x;        // t*4 + m
    const int t = b >> 2, m = b & 3;
    const float* src = (m == 0 ? Kw : m == 1 ? Qw : m == 2 ? Vw : Aw) + (size_t)t * 16384;
    unsigned short* dst = Wtbuf + (size_t)b * 16384;
    for (int i = threadIdx.x; i < 16384; i += blockDim.x) {
        const int k = i >> 7, nn = i & 127;
        dst[nn * 128 + k] = f2bf(src[i]);
    }
}

// ---------------- fused K/Q/V MFMA GEMM ----------------
__global__ __launch_bounds__(256) void gemm_kqv(const float* __restrict__ feat,
                                                const unsigned short* __restrict__ Wt,
                                                const float* __restrict__ Kb, const float* __restrict__ Qb,
                                                const float* __restrict__ Vb,
                                                unsigned short* __restrict__ Ko, unsigned short* __restrict__ Qo,
                                                unsigned short* __restrict__ Vo, int n)
{
    const int tid = threadIdx.x;
    const int w = tid >> 6, lane = tid & 63;
    const int r16 = lane & 15, kg = lane >> 4;
    const int wrow = blockIdx.x * 64 + w * 16;
    const int arow = min(wrow + r16, n - 1);

    short8 afr[4];
#pragma unroll
    for (int k0i = 0; k0i < 4; ++k0i) {
        const float* ap = feat + (size_t)arow * NDIM + k0i * 32 + kg * 8;
        const float4 lo = *(const float4*)ap;
        const float4 hi = *(const float4*)(ap + 4);
        short8 a;
        a[0] = (short)f2bf(lo.x); a[1] = (short)f2bf(lo.y);
        a[2] = (short)f2bf(lo.z); a[3] = (short)f2bf(lo.w);
        a[4] = (short)f2bf(hi.x); a[5] = (short)f2bf(hi.y);
        a[6] = (short)f2bf(hi.z); a[7] = (short)f2bf(hi.w);
        afr[k0i] = a;
    }

    const float* biases[3] = {Kb, Qb, Vb};
    unsigned short* outs[3] = {Ko, Qo, Vo};
#pragma unroll
    for (int m = 0; m < 3; ++m) {
        const unsigned short* wt = Wt + (size_t)m * 16384;
        f32x4 acc[8];
#pragma unroll
        for (int c = 0; c < 8; ++c) acc[c] = (f32x4){0.f, 0.f, 0.f, 0.f};
#pragma unroll
        for (int k0i = 0; k0i < 4; ++k0i)
#pragma unroll
            for (int c = 0; c < 8; ++c) {
                const short8 b = *(const short8*)(wt + (size_t)(16 * c + r16) * NDIM + k0i * 32 + kg * 8);
                acc[c] = __builtin_amdgcn_mfma_f32_16x16x32_bf16(afr[k0i], b, acc[c], 0, 0, 0);
            }
#pragma unroll
        for (int c = 0; c < 8; ++c) {
            const int col = 16 * c + r16;
            const float bb = biases[m][col];
#pragma unroll
            for (int j = 0; j < 4; ++j) {
                const int row = wrow + kg * 4 + j;
                if (row < n) outs[m][(size_t)row * NDIM + col] = f2bf(acc[c][j] + bb);
            }
        }
    }
}

// ---------------- output MFMA GEMM ----------------
template <bool AVG>
__global__ __launch_bounds__(256) void gemm_out2(const unsigned short* __restrict__ A1,
                                                 const unsigned short* __restrict__ A2,
                                                 const unsigned short* __restrict__ Wt,
                                                 const float* __restrict__ bias,
                                                 const float* __restrict__ feat,
                                                 const float* __restrict__ skip, int nid,
                                                 float* __restrict__ C, int n)
{
    const int tid = threadIdx.x;
    const int w = tid >> 6, lane = tid & 63;
    const int r16 = lane & 15, kg = lane >> 4;
    const int wrow = blockIdx.x * 64 + w * 16;
    const int arow = min(wrow + r16, n - 1);

    short8 afr[4];
#pragma unroll
    for (int k0i = 0; k0i < 4; ++k0i) {
        short8 a = *(const short8*)(A1 + (size_t)arow * NDIM + k0i * 32 + kg * 8);
        if (AVG) {
            const short8 b = *(const short8*)(A2 + (size_t)arow * NDIM + k0i * 32 + kg * 8);
#pragma unroll
            for (int j = 0; j < 8; ++j) {
                const float v = 0.5f * (bf2f((unsigned short)a[j]) + bf2f((unsigned short)b[j]));
                a[j] = (short)f2bf(v);
            }
        }
        afr[k0i] = a;
    }
    f32x4 acc[8];
#pragma unroll
    for (int c = 0; c < 8; ++c) acc[c] = (f32x4){0.f, 0.f, 0.f, 0.f};
#pragma unroll
    for (int k0i = 0; k0i < 4; ++k0i)
#pragma unroll
        for (int c = 0; c < 8; ++c) {
            const short8 b = *(const short8*)(Wt + (size_t)(16 * c + r16) * NDIM + k0i * 32 + kg * 8);
            acc[c] = __builtin_amdgcn_mfma_f32_16x16x32_bf16(afr[k0i], b, acc[c], 0, 0, 0);
        }
    const float sk = skip[nid];
    const float alpha = 1.f / (1.f + __expf(-sk));
    const float beta = 1.f - alpha;
#pragma unroll
    for (int c = 0; c < 8; ++c) {
        const int col = 16 * c + r16;
        const float bb = bias[col];
#pragma unroll
        for (int j = 0; j < 4; ++j) {
            const int row = wrow + kg * 4 + j;
            if (row < n)
                C[(size_t)row * NDIM + col] = (acc[c][j] + bb) * alpha + feat[(size_t)row * NDIM + col] * beta;
        }
    }
}

// ---------------- phase A: bucket edges into 8 dst-ranges (coalesced staging) ----------------
// staged entry: .x = dst | (src<<16)  .y = bits of (ev*ews + ebs)  (log2-folded edge coeff)
__global__ __launch_bounds__(256) void bucket3(
    const int* __restrict__ d0, const int* __restrict__ s0, const float* __restrict__ e0, int E0,
    const int* __restrict__ d1, const int* __restrict__ s1, const float* __restrict__ e1, int E1,
    const int* __restrict__ d2, const int* __restrict__ s2, const float* __restrict__ e2, int E2,
    unsigned int magic, const float* __restrict__ ew, const float* __restrict__ eb,
    uint2* __restrict__ stg, int cap, int* __restrict__ rcur)
{
    const int seg = blockIdx.y;
    const int* dst = seg == 0 ? d0 : (seg == 1 ? d1 : d2);
    const int* src = seg == 0 ? s0 : (seg == 1 ? s1 : s2);
    const float* ev = seg == 0 ? e0 : (seg == 1 ? e1 : e2);
    const int E = seg == 0 ? E0 : (seg == 1 ? E1 : E2);
    const int tid = threadIdx.x;
    const int lane = tid & 63;
    const float LOG2E = 1.4426950408889634f;
    const float ews = ew[0] * 0.25f * LOG2E;
    const float ebs = eb[0] * 0.25f * LOG2E;
    uint2* sbase = stg + (size_t)seg * NRNG * cap;
    int* rc = rcur + seg * NRNG;

    for (int base = blockIdx.x * blockDim.x; base < E; base += gridDim.x * blockDim.x) {
        const int i = base + tid;
        const bool valid = i < E;
        int d = 0, s = 0; float e = 0.f;
        if (valid) { d = dst[i]; s = src[i]; e = ev[i]; }
        const unsigned int r = valid ? min(__umulhi((unsigned int)d, magic), (unsigned int)(NRNG - 1)) : 0xFFu;
#pragma unroll
        for (int r0 = 0; r0 < NRNG; ++r0) {
            const unsigned long long mask = __ballot(r == (unsigned int)r0);
            const int cnt = __popcll(mask);
            if (cnt == 0) continue;
            const int leader = (int)(__ffsll((long long)mask) - 1);
            int wbase = 0;
            if (lane == leader) wbase = atomicAdd(&rc[r0], cnt);
            wbase = __shfl(wbase, leader);
            if (r == (unsigned int)r0) {
                const int off = __popcll(mask & ((1ull << lane) - 1ull));
                sbase[(size_t)r0 * cap + wbase + off] =
                    make_uint2((unsigned int)d | ((unsigned int)s << 16), __float_as_uint(e * ews + ebs));
            }
        }
    }
}

// ---------------- phase B1: histogram from staged (XCD-pinned by blockIdx&7) ----------------
__global__ __launch_bounds__(256) void histS(const uint2* __restrict__ stg, int cap,
                                             const int* __restrict__ rcur,
                                             int* __restrict__ p0, int* __restrict__ p1, int* __restrict__ p2)
{
    const int seg = blockIdx.y;
    int* pos = seg == 0 ? p0 : (seg == 1 ? p1 : p2);
    const int r = blockIdx.x & (NRNG - 1);
    const int cnt = rcur[seg * NRNG + r];
    const uint2* s = stg + ((size_t)seg * NRNG + r) * cap;
    const int stride = (gridDim.x >> 3) * blockDim.x;
    for (int i = (blockIdx.x >> 3) * blockDim.x + threadIdx.x; i < cnt; i += stride)
        atomicAdd(&pos[s[i].x & 0xFFFFu], 1);
}

// ---------------- scans (unchanged) ----------------
__global__ __launch_bounds__(256) void scan_partial(
    const int* __restrict__ c0, int nA, const int* __restrict__ c1, int nB,
    const int* __restrict__ c2, int nC, int* __restrict__ partial)
{
    const int seg = blockIdx.y;
    const int* c = seg == 0 ? c0 : (seg == 1 ? c1 : c2);
    const int n = seg == 0 ? nA : (seg == 1 ? nB : nC);
    const int beg = blockIdx.x * SCH;
    const int t = threadIdx.x;
    int s = 0;
    if (beg < n) {
        const int base_i = beg + t * 8;
#pragma unroll
        for (int j = 0; j < 8; ++j) {
            const int i = base_i + j;
            if (i < n) s += c[i];
        }
    }
#pragma unroll
    for (int o = 1; o < 64; o <<= 1) s += __shfl_xor(s, o);
    __shared__ int ws[4];
    const int lane = t & 63, w = t >> 6;
    if (lane == 0) ws[w] = s;
    __syncthreads();
    if (t == 0) partial[seg * MAXNB + blockIdx.x] = ws[0] + ws[1] + ws[2] + ws[3];
}

__global__ void scan_base(int* __restrict__ partial, int nA, int nB, int nC,
                          int* __restrict__ offA, int* __restrict__ offB, int* __restrict__ offC)
{
    const int seg = threadIdx.x;
    if (seg >= 3) return;
    const int n = seg == 0 ? nA : (seg == 1 ? nB : nC);
    int* off = seg == 0 ? offA : (seg == 1 ? offB : offC);
    const int nb = (n + SCH - 1) / SCH;
    int run = 0;
    for (int b = 0; b < nb; ++b) {
        const int v = partial[seg * MAXNB + b];
        partial[seg * MAXNB + b] = run;
        run += v;
    }
    off[n] = run;
}

__global__ __launch_bounds__(256) void scan_final(
    int* __restrict__ c0, int nA, int* __restrict__ offA,
    int* __restrict__ c1, int nB, int* __restrict__ offB,
    int* __restrict__ c2, int nC, int* __restrict__ offC,
    const int* __restrict__ partial)
{
    const int seg = blockIdx.y;
    int* c = seg == 0 ? c0 : (seg == 1 ? c1 : c2);
    int* off = seg == 0 ? offA : (seg == 1 ? offB : offC);
    const int n = seg == 0 ? nA : (seg == 1 ? nB : nC);
    const int beg = blockIdx.x * SCH;
    if (beg >= n) return;
    const int t = threadIdx.x, lane = t & 63, w = t >> 6;
    const int base_i = beg + t * 8;

    int v[8];
    int run = 0;
#pragma unroll
    for (int j = 0; j < 8; ++j) {
        const int i = base_i + j;
        const int x = (i < n) ? c[i] : 0;
        v[j] = run;
        run += x;
    }
    const int tsum = run;
    int x = tsum;
#pragma unroll
    for (int o = 1; o < 64; o <<= 1) {
        const int y = __shfl_up(x, o);
        if (lane >= o) x += y;
    }
    const int wexc = x - tsum;
    __shared__ int wsum[4];
    if (lane == 63) wsum[w] = x;
    __syncthreads();
    int wbase = 0;
    for (int i = 0; i < w; ++i) wbase += wsum[i];
    const int base = partial[seg * MAXNB + blockIdx.x] + wbase + wexc;
#pragma unroll
    for (int j = 0; j < 8; ++j) {
        const int i = base_i + j;
        if (i < n) {
            const int e = base + v[j];
            off[i] = e;
            c[i] = e;
        }
    }
}

// ---------------- phase B2: scatter from staged (XCD-pinned; writes confined per range) ----------------
__global__ __launch_bounds__(256) void scatterS(const uint2* __restrict__ stg, int cap,
                                                const int* __restrict__ rcur,
                                                int* __restrict__ p0, int* __restrict__ p1, int* __restrict__ p2,
                                                int2* __restrict__ g0, int2* __restrict__ g1, int2* __restrict__ g2)
{
    const int seg = blockIdx.y;
    int* pos = seg == 0 ? p0 : (seg == 1 ? p1 : p2);
    int2* edg = seg == 0 ? g0 : (seg == 1 ? g1 : g2);
    const int r = blockIdx.x & (NRNG - 1);
    const int cnt = rcur[seg * NRNG + r];
    const uint2* s = stg + ((size_t)seg * NRNG + r) * cap;
    const int stride = (gridDim.x >> 3) * blockDim.x;
    for (int i = (blockIdx.x >> 3) * blockDim.x + threadIdx.x; i < cnt; i += stride) {
        const uint2 v = s[i];
        const int d = (int)(v.x & 0xFFFFu);
        const int p = atomicAdd(&pos[d], 1);
        edg[p] = make_int2((int)(v.x >> 16), (int)v.y);
    }
}

// ---------------- edge aggregation v3 (folded edge coeff) ----------------
__global__ __launch_bounds__(256) void edge_agg3(
    const int* __restrict__ off0, const int2* __restrict__ edg0,
    const unsigned short* __restrict__ K0e, const unsigned short* __restrict__ Q0e,
    const unsigned short* __restrict__ V0e, unsigned short* __restrict__ out0, int nd0,
    const int* __restrict__ off1, const int2* __restrict__ edg1,
    const unsigned short* __restrict__ K1e, const unsigned short* __restrict__ Q1e,
    const unsigned short* __restrict__ V1e, unsigned short* __restrict__ out1, int nd1,
    const int* __restrict__ off2, const int2* __restrict__ edg2,
    const unsigned short* __restrict__ K2e, const unsigned short* __restrict__ Q2e,
    const unsigned short* __restrict__ V2e, unsigned short* __restrict__ out2, int nd2)
{
    const int seg = blockIdx.y;
    const int* off = seg == 0 ? off0 : (seg == 1 ? off1 : off2);
    const int2* edg = seg == 0 ? edg0 : (seg == 1 ? edg1 : edg2);
    const unsigned short* K = seg == 0 ? K0e : (seg == 1 ? K1e : K2e);
    const unsigned short* Q = seg == 0 ? Q0e : (seg == 1 ? Q1e : Q2e);
    const unsigned short* V = seg == 0 ? V0e : (seg == 1 ? V1e : V2e);
    unsigned short* aggb = seg == 0 ? out0 : (seg == 1 ? out1 : out2);
    const int n_dst = seg == 0 ? nd0 : (seg == 1 ? nd1 : nd2);

    const int wv = (blockIdx.x * blockDim.x + threadIdx.x) >> 6;
    const int lane = threadIdx.x & 63;
    const int half = lane >> 5, l5 = lane & 31;
    const int dst = 2 * wv + half;
    const bool valid = dst < n_dst;
    int beg = 0, len = 0;
    if (valid) { beg = off[dst]; len = off[dst + 1] - beg; }
    const int maxLen = max(len, __shfl_xor(len, 32));
    if (maxLen == 0) {
        if (valid) *(ushort4*)(aggb + (size_t)dst * NDIM + 4 * l5) = (ushort4){0, 0, 0, 0};
        return;
    }
    float qx = 0.f, qy = 0.f, qz = 0.f, qw = 0.f;
    if (valid) {
        const ushort4 qr = *(const ushort4*)(Q + (size_t)dst * NDIM + 4 * l5);
        qx = bf2f(qr.x); qy = bf2f(qr.y); qz = bf2f(qr.z); qw = bf2f(qr.w);
    }
    float z = 0.f, a0 = 0.f, a1 = 0.f, a2 = 0.f, a3 = 0.f;

    int2 ec = (l5 < len) ? edg[beg + l5] : make_int2(0, 0);
    for (int t0 = 0; t0 < maxLen; t0 += 32) {
        int2 en = make_int2(0, 0);
        const int t0n = t0 + 32;
        if (t0n < maxLen && t0n + l5 < len) en = edg[beg + t0n + l5];
        const int lim = min(32, maxLen - t0);
        for (int u = 0; u < lim; ++u) {
            const int sl = (half << 5) + u;
            const int s = __shfl(ec.x, sl);
            const float w = __int_as_float(__shfl(ec.y, sl));   // pre-folded coeff
            const bool act = (t0 + u) < len;
            const ushort4 kr = *(const ushort4*)(K + (size_t)s * NDIM + 4 * l5);
            const ushort4 vr = *(const ushort4*)(V + (size_t)s * NDIM + 4 * l5);
            float d = qx * bf2f(kr.x) + qy * bf2f(kr.y) + qz * bf2f(kr.z) + qw * bf2f(kr.w);
            d += __shfl_xor(d, 1);
            d += __shfl_xor(d, 2);
            const float p = act ? exp2f(d * w) : 0.f;           // no-max softmax (scores bounded)
            z += p;
            a0 += p * bf2f(vr.x);
            a1 += p * bf2f(vr.y);
            a2 += p * bf2f(vr.z);
            a3 += p * bf2f(vr.w);
        }
        ec = en;
    }
    if (valid) {
        const float inv = (len > 0) ? 1.f / z : 0.f;
        ushort4 o;
        o.x = f2bf(a0 * inv); o.y = f2bf(a1 * inv);
        o.z = f2bf(a2 * inv); o.w = f2bf(a3 * inv);
        *(ushort4*)(aggb + (size_t)dst * NDIM + 4 * l5) = o;
    }
}

extern "C" void kernel_launch(void* const* d_in, const int* in_sizes, int n_in,
                              void* d_out, int out_size, void* d_ws, size_t ws_size,
                              hipStream_t stream)
{
    const float* feat0 = (const float*)d_in[0];
    const float* feat1 = (const float*)d_in[1];
    const float* ev0 = (const float*)d_in[2];
    const float* ev1 = (const float*)d_in[3];
    const float* ev2 = (const float*)d_in[4];
    const int* src0 = (const int*)d_in[5];
    const int* dst0 = (const int*)d_in[6];
    const int* src1 = (const int*)d_in[7];
    const int* dst1 = (const int*)d_in[8];
    const int* src2 = (const int*)d_in[9];
    const int* dst2 = (const int*)d_in[10];
    const float* Kw = (const float*)d_in[11];
    const float* Kb = (const float*)d_in[12];
    const float* Qw = (const float*)d_in[13];
    const float* Qb = (const float*)d_in[14];
    const float* Vw = (const float*)d_in[15];
    const float* Vb = (const float*)d_in[16];
    const float* Aw = (const float*)d_in[17];
    const float* Ab = (const float*)d_in[18];
    const float* ew = (const float*)d_in[19];
    const float* eb = (const float*)d_in[20];
    const float* skip = (const float*)d_in[21];

    const int n0 = in_sizes[0] / NDIM;
    const int n1 = in_sizes[1] / NDIM;
    const int E0 = in_sizes[5];
    const int E1 = in_sizes[7];
    const int E2 = in_sizes[9];
    const int Emax = max(E0, max(E1, E2));
    const int cap = Emax / NRNG + 16384;            // per-range staging capacity (>50 sigma slack)
    // dst-range magic: range = umulhi(d, magic) ~= d*8/n
    const unsigned int magic = (unsigned int)(((8ull << 32) + (unsigned)max(n0, n1) - 1) / (unsigned)max(n0, n1));

    auto rup = [](size_t b) { return (b + 255) & ~size_t(255); };
    const size_t need =
        rup((size_t)8 * 16384 * 2) +
        rup((size_t)n0 * NDIM * 2) * 3 +
        rup((size_t)n1 * NDIM * 2) * 3 +
        rup((size_t)n1 * NDIM * 2) +
        rup((size_t)n0 * NDIM * 2) * 2 +
        rup((size_t)(n1 + 1) * 4) +
        rup((size_t)(n0 + 1) * 4) * 2 +
        rup((size_t)(n1 + n0 + n0 + 64) * 4) +
        rup((size_t)3 * MAXNB * 4) +
        rup((size_t)3 * NRNG * cap * 8) +
        rup((size_t)E0 * 8) + rup((size_t)E1 * 8) + rup((size_t)E2 * 8);
    if (ws_size < need) return;

    char* p = (char*)d_ws;
    auto alloc = [&](size_t bytes) -> char* {
        char* r = p;
        p += (bytes + 255) & ~size_t(255);
        return r;
    };
    unsigned short* Wtbuf = (unsigned short*)alloc((size_t)8 * 16384 * 2);
    unsigned short* K0 = (unsigned short*)alloc((size_t)n0 * NDIM * 2);
    unsigned short* Q0 = (unsigned short*)alloc((size_t)n0 * NDIM * 2);
    unsigned short* V0 = (unsigned short*)alloc((size_t)n0 * NDIM * 2);
    unsigned short* K1 = (unsigned short*)alloc((size_t)n1 * NDIM * 2);
    unsigned short* Q1 = (unsigned short*)alloc((size_t)n1 * NDIM * 2);
    unsigned short* V1 = (unsigned short*)alloc((size_t)n1 * NDIM * 2);
    unsigned short* aggb1  = (unsigned short*)alloc((size_t)n1 * NDIM * 2);
    unsigned short* aggb0a = (unsigned short*)alloc((size_t)n0 * NDIM * 2);
    unsigned short* aggb0b = (unsigned short*)alloc((size_t)n0 * NDIM * 2);
    int* off0 = (int*)alloc((size_t)(n1 + 1) * 4);
    int* off1 = (int*)alloc((size_t)(n0 + 1) * 4);
    int* off2 = (int*)alloc((size_t)(n0 + 1) * 4);
    int* posA = (int*)alloc((size_t)(n1 + n0 + n0 + 64) * 4);   // pos0|pos1|pos2|rcur(24)
    int* pos0 = posA;
    int* pos1 = posA + n1;
    int* pos2 = posA + n1 + n0;
    int* rcur = posA + n1 + n0 + n0;
    int* partial = (int*)alloc((size_t)3 * MAXNB * 4);
    uint2* stg = (uint2*)alloc((size_t)3 * NRNG * cap * 8);
    int2* edg0 = (int2*)alloc((size_t)E0 * 8);
    int2* edg1 = (int2*)alloc((size_t)E1 * 8);
    int2* edg2 = (int2*)alloc((size_t)E2 * 8);

    dim3 blk(256);
    dim3 g0((n0 + 63) / 64), g1((n1 + 63) / 64);

    wt_prep<<<8, 256, 0, stream>>>(Kw, Qw, Vw, Aw, Wtbuf);
    gemm_kqv<<<g0, blk, 0, stream>>>(feat0, Wtbuf,             Kb,        Qb,        Vb,        K0, Q0, V0, n0);
    gemm_kqv<<<g1, blk, 0, stream>>>(feat1, Wtbuf + 4 * 16384, Kb + NDIM, Qb + NDIM, Vb + NDIM, K1, Q1, V1, n1);

    hipMemsetAsync(posA, 0, (size_t)(n1 + n0 + n0 + 64) * 4, stream);

    bucket3<<<dim3(1024, 3), blk, 0, stream>>>(dst0, src0, ev0, E0,
                                               dst1, src1, ev1, E1,
                                               dst2, src2, ev2, E2,
                                               magic, ew, eb, stg, cap, rcur);
    histS<<<dim3(1024, 3), blk, 0, stream>>>(stg, cap, rcur, pos0, pos1, pos2);

    const int nmax = (n0 > n1) ? n0 : n1;
    const int nb = (nmax + SCH - 1) / SCH;
    scan_partial<<<dim3(nb, 3), blk, 0, stream>>>(pos0, n1, pos1, n0, pos2, n0, partial);
    scan_base<<<1, 64, 0, stream>>>(partial, n1, n0, n0, off0, off1, off2);
    scan_final<<<dim3(nb, 3), blk, 0, stream>>>(pos0, n1, off0, pos1, n0, off1, pos2, n0, off2, partial);

    scatterS<<<dim3(1024, 3), blk, 0, stream>>>(stg, cap, rcur, pos0, pos1, pos2, edg0, edg1, edg2);

    const int ebx = ((nmax + 1) / 2 + 3) / 4;
    edge_agg3<<<dim3(ebx, 3), blk, 0, stream>>>(
        off0, edg0, K0, Q1, V0, aggb1, n1,
        off1, edg1, K1, Q0, V1, aggb0a, n0,
        off2, edg2, K0, Q0, V0, aggb0b, n0);

    float* out = (float*)d_out;
    gemm_out2<true ><<<g0, blk, 0, stream>>>(aggb0a, aggb0b, Wtbuf + 3 * 16384, Ab,        feat0, skip, 0, out, n0);
    gemm_out2<false><<<g1, blk, 0, stream>>>(aggb1,  nullptr, Wtbuf + 7 * 16384, Ab + NDIM, feat1, skip, 1, out + (size_t)n0 * NDIM, n1);
}

// Round 12
// 618.453 us; speedup vs baseline: 6.2256x; 6.2256x over previous
//
#include <hip/hip_runtime.h>
#include <hip/hip_bf16.h>
#include <math.h>

// HEAT layer. Round 12: deterministic atomic-free bucketing (count/scan/write,
// ballot-prefix, zero contention) replacing round-10's atomic-append bucket3
// (which serialized on 24 global counters: 3253us). Phase B (XCD-pinned
// histS/scatterS ~132us measured) and edge_agg3 / MFMA GEMMs unchanged.

#define NDIM 128
#define SCH 2048
#define MAXNB 64
#define NRNG 8
#define NBK 512          // bucket blocks per seg -> U = NBK*4 wave-units
#define UNITS (NBK * 4)

typedef __attribute__((ext_vector_type(8))) short short8;
typedef __attribute__((ext_vector_type(4))) float f32x4;

__device__ __forceinline__ float bf2f(unsigned short u) {
    union { unsigned int i; float f; } x; x.i = ((unsigned int)u) << 16; return x.f;
}
__device__ __forceinline__ unsigned short f2bf(float f) {
    unsigned int u = __float_as_uint(f);
    unsigned int r = (u + 0x7FFFu + ((u >> 16) & 1u)) >> 16;   // RNE
    return (unsigned short)r;
}

// ---------------- weight prep: 8 mats f32[k][n] -> bf16 [n][k] ----------------
__global__ void wt_prep(const float* __restrict__ Kw, const float* __restrict__ Qw,
                        const float* __restrict__ Vw, const float* __restrict__ Aw,
                        unsigned short* __restrict__ Wtbuf)
{
    const int b = blockIdx.x;        // t*4 + m
    const int t = b >> 2, m = b & 3;
    const float* src = (m == 0 ? Kw : m == 1 ? Qw : m == 2 ? Vw : Aw) + (size_t)t * 16384;
    unsigned short* dst = Wtbuf + (size_t)b * 16384;
    for (int i = threadIdx.x; i < 16384; i += blockDim.x) {
        const int k = i >> 7, nn = i & 127;
        dst[nn * 128 + k] = f2bf(src[i]);
    }
}

// ---------------- fused K/Q/V MFMA GEMM ----------------
__global__ __launch_bounds__(256) void gemm_kqv(const float* __restrict__ feat,
                                                const unsigned short* __restrict__ Wt,
                                                const float* __restrict__ Kb, const float* __restrict__ Qb,
                                                const float* __restrict__ Vb,
                                                unsigned short* __restrict__ Ko, unsigned short* __restrict__ Qo,
                                                unsigned short* __restrict__ Vo, int n)
{
    const int tid = threadIdx.x;
    const int w = tid >> 6, lane = tid & 63;
    const int r16 = lane & 15, kg = lane >> 4;
    const int wrow = blockIdx.x * 64 + w * 16;
    const int arow = min(wrow + r16, n - 1);

    short8 afr[4];
#pragma unroll
    for (int k0i = 0; k0i < 4; ++k0i) {
        const float* ap = feat + (size_t)arow * NDIM + k0i * 32 + kg * 8;
        const float4 lo = *(const float4*)ap;
        const float4 hi = *(const float4*)(ap + 4);
        short8 a;
        a[0] = (short)f2bf(lo.x); a[1] = (short)f2bf(lo.y);
        a[2] = (short)f2bf(lo.z); a[3] = (short)f2bf(lo.w);
        a[4] = (short)f2bf(hi.x); a[5] = (short)f2bf(hi.y);
        a[6] = (short)f2bf(hi.z); a[7] = (short)f2bf(hi.w);
        afr[k0i] = a;
    }

    const float* biases[3] = {Kb, Qb, Vb};
    unsigned short* outs[3] = {Ko, Qo, Vo};
#pragma unroll
    for (int m = 0; m < 3; ++m) {
        const unsigned short* wt = Wt + (size_t)m * 16384;
        f32x4 acc[8];
#pragma unroll
        for (int c = 0; c < 8; ++c) acc[c] = (f32x4){0.f, 0.f, 0.f, 0.f};
#pragma unroll
        for (int k0i = 0; k0i < 4; ++k0i)
#pragma unroll
            for (int c = 0; c < 8; ++c) {
                const short8 b = *(const short8*)(wt + (size_t)(16 * c + r16) * NDIM + k0i * 32 + kg * 8);
                acc[c] = __builtin_amdgcn_mfma_f32_16x16x32_bf16(afr[k0i], b, acc[c], 0, 0, 0);
            }
#pragma unroll
        for (int c = 0; c < 8; ++c) {
            const int col = 16 * c + r16;
            const float bb = biases[m][col];
#pragma unroll
            for (int j = 0; j < 4; ++j) {
                const int row = wrow + kg * 4 + j;
                if (row < n) outs[m][(size_t)row * NDIM + col] = f2bf(acc[c][j] + bb);
            }
        }
    }
}

// ---------------- output MFMA GEMM ----------------
template <bool AVG>
__global__ __launch_bounds__(256) void gemm_out2(const unsigned short* __restrict__ A1,
                                                 const unsigned short* __restrict__ A2,
                                                 const unsigned short* __restrict__ Wt,
                                                 const float* __restrict__ bias,
                                                 const float* __restrict__ feat,
                                                 const float* __restrict__ skip, int nid,
                                                 float* __restrict__ C, int n)
{
    const int tid = threadIdx.x;
    const int w = tid >> 6, lane = tid & 63;
    const int r16 = lane & 15, kg = lane >> 4;
    const int wrow = blockIdx.x * 64 + w * 16;
    const int arow = min(wrow + r16, n - 1);

    short8 afr[4];
#pragma unroll
    for (int k0i = 0; k0i < 4; ++k0i) {
        short8 a = *(const short8*)(A1 + (size_t)arow * NDIM + k0i * 32 + kg * 8);
        if (AVG) {
            const short8 b = *(const short8*)(A2 + (size_t)arow * NDIM + k0i * 32 + kg * 8);
#pragma unroll
            for (int j = 0; j < 8; ++j) {
                const float v = 0.5f * (bf2f((unsigned short)a[j]) + bf2f((unsigned short)b[j]));
                a[j] = (short)f2bf(v);
            }
        }
        afr[k0i] = a;
    }
    f32x4 acc[8];
#pragma unroll
    for (int c = 0; c < 8; ++c) acc[c] = (f32x4){0.f, 0.f, 0.f, 0.f};
#pragma unroll
    for (int k0i = 0; k0i < 4; ++k0i)
#pragma unroll
        for (int c = 0; c < 8; ++c) {
            const short8 b = *(const short8*)(Wt + (size_t)(16 * c + r16) * NDIM + k0i * 32 + kg * 8);
            acc[c] = __builtin_amdgcn_mfma_f32_16x16x32_bf16(afr[k0i], b, acc[c], 0, 0, 0);
        }
    const float sk = skip[nid];
    const float alpha = 1.f / (1.f + __expf(-sk));
    const float beta = 1.f - alpha;
#pragma unroll
    for (int c = 0; c < 8; ++c) {
        const int col = 16 * c + r16;
        const float bb = bias[col];
#pragma unroll
        for (int j = 0; j < 4; ++j) {
            const int row = wrow + kg * 4 + j;
            if (row < n)
                C[(size_t)row * NDIM + col] = (acc[c][j] + bb) * alpha + feat[(size_t)row * NDIM + col] * beta;
        }
    }
}

// ---------------- phase A1: per-unit range counts (ballot, zero atomics) ----------------
__global__ __launch_bounds__(256) void bucket_count(
    const int* __restrict__ d0, int E0, const int* __restrict__ d1, int E1,
    const int* __restrict__ d2, int E2, unsigned int magic, int* __restrict__ cnts)
{
    const int seg = blockIdx.y;
    const int* dst = seg == 0 ? d0 : (seg == 1 ? d1 : d2);
    const int E = seg == 0 ? E0 : (seg == 1 ? E1 : E2);
    const int unit = blockIdx.x * 4 + (threadIdx.x >> 6);
    const int lane = threadIdx.x & 63;
    const int span = (E + UNITS - 1) / UNITS;
    const int b = unit * span;
    const int e = min(b + span, E);

    int run[NRNG];
#pragma unroll
    for (int r0 = 0; r0 < NRNG; ++r0) run[r0] = 0;
    for (int i0 = b; i0 < e; i0 += 64) {
        const int i = i0 + lane;
        const bool v = i < e;
        const int d = v ? dst[i] : 0;
        const unsigned int r = v ? min(__umulhi((unsigned int)d, magic), (unsigned int)(NRNG - 1)) : 0xFFu;
#pragma unroll
        for (int r0 = 0; r0 < NRNG; ++r0)
            run[r0] += __popcll(__ballot(r == (unsigned int)r0));
    }
    if (lane == 0) {
        int* c = cnts + ((size_t)seg * UNITS + unit) * NRNG;
#pragma unroll
        for (int r0 = 0; r0 < NRNG; ++r0) c[r0] = run[r0];
    }
}

// ---------------- phase A2: exclusive scan of unit counts per (seg,range); totals -> rcur ----------------
__global__ __launch_bounds__(256) void bucket_scan(int* __restrict__ cnts, int* __restrict__ rcur)
{
    const int seg = blockIdx.x >> 3;
    const int r = blockIdx.x & 7;
    const int t = threadIdx.x, lane = t & 63, w = t >> 6;

    int v[8];
    int run = 0;
#pragma unroll
    for (int j = 0; j < 8; ++j) {
        const int u = t * 8 + j;
        const int x = cnts[((size_t)seg * UNITS + u) * NRNG + r];
        v[j] = run;
        run += x;
    }
    const int tsum = run;
    int x = tsum;
#pragma unroll
    for (int o = 1; o < 64; o <<= 1) {
        const int y = __shfl_up(x, o);
        if (lane >= o) x += y;
    }
    const int wexc = x - tsum;
    __shared__ int wsum[4];
    if (lane == 63) wsum[w] = x;
    __syncthreads();
    int wbase = 0;
    for (int i = 0; i < w; ++i) wbase += wsum[i];
    const int base = wbase + wexc;
#pragma unroll
    for (int j = 0; j < 8; ++j) {
        const int u = t * 8 + j;
        cnts[((size_t)seg * UNITS + u) * NRNG + r] = base + v[j];
    }
    if (t == 255) rcur[seg * NRNG + r] = base + tsum;
}

// ---------------- phase A3: deterministic staged write (ballot prefix + scanned base) ----------------
__global__ __launch_bounds__(256) void bucket_write(
    const int* __restrict__ d0, const int* __restrict__ s0, const float* __restrict__ e0, int E0,
    const int* __restrict__ d1, const int* __restrict__ s1, const float* __restrict__ e1, int E1,
    const int* __restrict__ d2, const int* __restrict__ s2, const float* __restrict__ e2, int E2,
    unsigned int magic, const float* __restrict__ ew, const float* __restrict__ eb,
    const int* __restrict__ cnts, uint2* __restrict__ stg, int cap)
{
    const int seg = blockIdx.y;
    const int* dst = seg == 0 ? d0 : (seg == 1 ? d1 : d2);
    const int* src = seg == 0 ? s0 : (seg == 1 ? s1 : s2);
    const float* ev = seg == 0 ? e0 : (seg == 1 ? e1 : e2);
    const int E = seg == 0 ? E0 : (seg == 1 ? E1 : E2);
    const int unit = blockIdx.x * 4 + (threadIdx.x >> 6);
    const int lane = threadIdx.x & 63;
    const int span = (E + UNITS - 1) / UNITS;
    const int b = unit * span;
    const int e = min(b + span, E);
    const float LOG2E = 1.4426950408889634f;
    const float ews = ew[0] * 0.25f * LOG2E;
    const float ebs = eb[0] * 0.25f * LOG2E;
    uint2* sbase = stg + (size_t)seg * NRNG * cap;

    int run[NRNG];
    {
        const int* c = cnts + ((size_t)seg * UNITS + unit) * NRNG;
#pragma unroll
        for (int r0 = 0; r0 < NRNG; ++r0) run[r0] = c[r0];
    }
    for (int i0 = b; i0 < e; i0 += 64) {
        const int i = i0 + lane;
        const bool v = i < e;
        int d = 0, s = 0; float ee = 0.f;
        if (v) { d = dst[i]; s = src[i]; ee = ev[i]; }
        const unsigned int r = v ? min(__umulhi((unsigned int)d, magic), (unsigned int)(NRNG - 1)) : 0xFFu;
#pragma unroll
        for (int r0 = 0; r0 < NRNG; ++r0) {
            const unsigned long long m = __ballot(r == (unsigned int)r0);
            if (m == 0ull) continue;
            if (r == (unsigned int)r0) {
                const int off = run[r0] + __popcll(m & ((1ull << lane) - 1ull));
                sbase[(size_t)r0 * cap + off] =
                    make_uint2((unsigned int)d | ((unsigned int)s << 16), __float_as_uint(ee * ews + ebs));
            }
            run[r0] += __popcll(m);
        }
    }
}

// ---------------- phase B1: histogram from staged (XCD-pinned by blockIdx&7) ----------------
__global__ __launch_bounds__(256) void histS(const uint2* __restrict__ stg, int cap,
                                             const int* __restrict__ rcur,
                                             int* __restrict__ p0, int* __restrict__ p1, int* __restrict__ p2)
{
    const int seg = blockIdx.y;
    int* pos = seg == 0 ? p0 : (seg == 1 ? p1 : p2);
    const int r = blockIdx.x & (NRNG - 1);
    const int cnt = rcur[seg * NRNG + r];
    const uint2* s = stg + ((size_t)seg * NRNG + r) * cap;
    const int stride = (gridDim.x >> 3) * blockDim.x;
    for (int i = (blockIdx.x >> 3) * blockDim.x + threadIdx.x; i < cnt; i += stride)
        atomicAdd(&pos[s[i].x & 0xFFFFu], 1);
}

// ---------------- scans (unchanged) ----------------
__global__ __launch_bounds__(256) void scan_partial(
    const int* __restrict__ c0, int nA, const int* __restrict__ c1, int nB,
    const int* __restrict__ c2, int nC, int* __restrict__ partial)
{
    const int seg = blockIdx.y;
    const int* c = seg == 0 ? c0 : (seg == 1 ? c1 : c2);
    const int n = seg == 0 ? nA : (seg == 1 ? nB : nC);
    const int beg = blockIdx.x * SCH;
    const int t = threadIdx.x;
    int s = 0;
    if (beg < n) {
        const int base_i = beg + t * 8;
#pragma unroll
        for (int j = 0; j < 8; ++j) {
            const int i = base_i + j;
            if (i < n) s += c[i];
        }
    }
#pragma unroll
    for (int o = 1; o < 64; o <<= 1) s += __shfl_xor(s, o);
    __shared__ int ws[4];
    const int lane = t & 63, w = t >> 6;
    if (lane == 0) ws[w] = s;
    __syncthreads();
    if (t == 0) partial[seg * MAXNB + blockIdx.x] = ws[0] + ws[1] + ws[2] + ws[3];
}

__global__ void scan_base(int* __restrict__ partial, int nA, int nB, int nC,
                          int* __restrict__ offA, int* __restrict__ offB, int* __restrict__ offC)
{
    const int seg = threadIdx.x;
    if (seg >= 3) return;
    const int n = seg == 0 ? nA : (seg == 1 ? nB : nC);
    int* off = seg == 0 ? offA : (seg == 1 ? offB : offC);
    const int nb = (n + SCH - 1) / SCH;
    int run = 0;
    for (int b = 0; b < nb; ++b) {
        const int v = partial[seg * MAXNB + b];
        partial[seg * MAXNB + b] = run;
        run += v;
    }
    off[n] = run;
}

__global__ __launch_bounds__(256) void scan_final(
    int* __restrict__ c0, int nA, int* __restrict__ offA,
    int* __restrict__ c1, int nB, int* __restrict__ offB,
    int* __restrict__ c2, int nC, int* __restrict__ offC,
    const int* __restrict__ partial)
{
    const int seg = blockIdx.y;
    int* c = seg == 0 ? c0 : (seg == 1 ? c1 : c2);
    int* off = seg == 0 ? offA : (seg == 1 ? offB : offC);
    const int n = seg == 0 ? nA : (seg == 1 ? nB : nC);
    const int beg = blockIdx.x * SCH;
    if (beg >= n) return;
    const int t = threadIdx.x, lane = t & 63, w = t >> 6;
    const int base_i = beg + t * 8;

    int v[8];
    int run = 0;
#pragma unroll
    for (int j = 0; j < 8; ++j) {
        const int i = base_i + j;
        const int x = (i < n) ? c[i] : 0;
        v[j] = run;
        run += x;
    }
    const int tsum = run;
    int x = tsum;
#pragma unroll
    for (int o = 1; o < 64; o <<= 1) {
        const int y = __shfl_up(x, o);
        if (lane >= o) x += y;
    }
    const int wexc = x - tsum;
    __shared__ int wsum[4];
    if (lane == 63) wsum[w] = x;
    __syncthreads();
    int wbase = 0;
    for (int i = 0; i < w; ++i) wbase += wsum[i];
    const int base = partial[seg * MAXNB + blockIdx.x] + wbase + wexc;
#pragma unroll
    for (int j = 0; j < 8; ++j) {
        const int i = base_i + j;
        if (i < n) {
            const int e = base + v[j];
            off[i] = e;
            c[i] = e;
        }
    }
}

// ---------------- phase B2: scatter from staged (XCD-pinned; writes confined per range) ----------------
__global__ __launch_bounds__(256) void scatterS(const uint2* __restrict__ stg, int cap,
                                                const int* __restrict__ rcur,
                                                int* __restrict__ p0, int* __restrict__ p1, int* __restrict__ p2,
                                                int2* __restrict__ g0, int2* __restrict__ g1, int2* __restrict__ g2)
{
    const int seg = blockIdx.y;
    int* pos = seg == 0 ? p0 : (seg == 1 ? p1 : p2);
    int2* edg = seg == 0 ? g0 : (seg == 1 ? g1 : g2);
    const int r = blockIdx.x & (NRNG - 1);
    const int cnt = rcur[seg * NRNG + r];
    const uint2* s = stg + ((size_t)seg * NRNG + r) * cap;
    const int stride = (gridDim.x >> 3) * blockDim.x;
    for (int i = (blockIdx.x >> 3) * blockDim.x + threadIdx.x; i < cnt; i += stride) {
        const uint2 v = s[i];
        const int d = (int)(v.x & 0xFFFFu);
        const int p = atomicAdd(&pos[d], 1);
        edg[p] = make_int2((int)(v.x >> 16), (int)v.y);
    }
}

// ---------------- edge aggregation v3 (folded edge coeff) ----------------
__global__ __launch_bounds__(256) void edge_agg3(
    const int* __restrict__ off0, const int2* __restrict__ edg0,
    const unsigned short* __restrict__ K0e, const unsigned short* __restrict__ Q0e,
    const unsigned short* __restrict__ V0e, unsigned short* __restrict__ out0, int nd0,
    const int* __restrict__ off1, const int2* __restrict__ edg1,
    const unsigned short* __restrict__ K1e, const unsigned short* __restrict__ Q1e,
    const unsigned short* __restrict__ V1e, unsigned short* __restrict__ out1, int nd1,
    const int* __restrict__ off2, const int2* __restrict__ edg2,
    const unsigned short* __restrict__ K2e, const unsigned short* __restrict__ Q2e,
    const unsigned short* __restrict__ V2e, unsigned short* __restrict__ out2, int nd2)
{
    const int seg = blockIdx.y;
    const int* off = seg == 0 ? off0 : (seg == 1 ? off1 : off2);
    const int2* edg = seg == 0 ? edg0 : (seg == 1 ? edg1 : edg2);
    const unsigned short* K = seg == 0 ? K0e : (seg == 1 ? K1e : K2e);
    const unsigned short* Q = seg == 0 ? Q0e : (seg == 1 ? Q1e : Q2e);
    const unsigned short* V = seg == 0 ? V0e : (seg == 1 ? V1e : V2e);
    unsigned short* aggb = seg == 0 ? out0 : (seg == 1 ? out1 : out2);
    const int n_dst = seg == 0 ? nd0 : (seg == 1 ? nd1 : nd2);

    const int wv = (blockIdx.x * blockDim.x + threadIdx.x) >> 6;
    const int lane = threadIdx.x & 63;
    const int half = lane >> 5, l5 = lane & 31;
    const int dst = 2 * wv + half;
    const bool valid = dst < n_dst;
    int beg = 0, len = 0;
    if (valid) { beg = off[dst]; len = off[dst + 1] - beg; }
    const int maxLen = max(len, __shfl_xor(len, 32));
    if (maxLen == 0) {
        if (valid) *(ushort4*)(aggb + (size_t)dst * NDIM + 4 * l5) = (ushort4){0, 0, 0, 0};
        return;
    }
    float qx = 0.f, qy = 0.f, qz = 0.f, qw = 0.f;
    if (valid) {
        const ushort4 qr = *(const ushort4*)(Q + (size_t)dst * NDIM + 4 * l5);
        qx = bf2f(qr.x); qy = bf2f(qr.y); qz = bf2f(qr.z); qw = bf2f(qr.w);
    }
    float z = 0.f, a0 = 0.f, a1 = 0.f, a2 = 0.f, a3 = 0.f;

    int2 ec = (l5 < len) ? edg[beg + l5] : make_int2(0, 0);
    for (int t0 = 0; t0 < maxLen; t0 += 32) {
        int2 en = make_int2(0, 0);
        const int t0n = t0 + 32;
        if (t0n < maxLen && t0n + l5 < len) en = edg[beg + t0n + l5];
        const int lim = min(32, maxLen - t0);
        for (int u = 0; u < lim; ++u) {
            const int sl = (half << 5) + u;
            const int s = __shfl(ec.x, sl);
            const float w = __int_as_float(__shfl(ec.y, sl));   // pre-folded coeff
            const bool act = (t0 + u) < len;
            const ushort4 kr = *(const ushort4*)(K + (size_t)s * NDIM + 4 * l5);
            const ushort4 vr = *(const ushort4*)(V + (size_t)s * NDIM + 4 * l5);
            float d = qx * bf2f(kr.x) + qy * bf2f(kr.y) + qz * bf2f(kr.z) + qw * bf2f(kr.w);
            d += __shfl_xor(d, 1);
            d += __shfl_xor(d, 2);
            const float p = act ? exp2f(d * w) : 0.f;           // no-max softmax (scores bounded)
            z += p;
            a0 += p * bf2f(vr.x);
            a1 += p * bf2f(vr.y);
            a2 += p * bf2f(vr.z);
            a3 += p * bf2f(vr.w);
        }
        ec = en;
    }
    if (valid) {
        const float inv = (len > 0) ? 1.f / z : 0.f;
        ushort4 o;
        o.x = f2bf(a0 * inv); o.y = f2bf(a1 * inv);
        o.z = f2bf(a2 * inv); o.w = f2bf(a3 * inv);
        *(ushort4*)(aggb + (size_t)dst * NDIM + 4 * l5) = o;
    }
}

extern "C" void kernel_launch(void* const* d_in, const int* in_sizes, int n_in,
                              void* d_out, int out_size, void* d_ws, size_t ws_size,
                              hipStream_t stream)
{
    const float* feat0 = (const float*)d_in[0];
    const float* feat1 = (const float*)d_in[1];
    const float* ev0 = (const float*)d_in[2];
    const float* ev1 = (const float*)d_in[3];
    const float* ev2 = (const float*)d_in[4];
    const int* src0 = (const int*)d_in[5];
    const int* dst0 = (const int*)d_in[6];
    const int* src1 = (const int*)d_in[7];
    const int* dst1 = (const int*)d_in[8];
    const int* src2 = (const int*)d_in[9];
    const int* dst2 = (const int*)d_in[10];
    const float* Kw = (const float*)d_in[11];
    const float* Kb = (const float*)d_in[12];
    const float* Qw = (const float*)d_in[13];
    const float* Qb = (const float*)d_in[14];
    const float* Vw = (const float*)d_in[15];
    const float* Vb = (const float*)d_in[16];
    const float* Aw = (const float*)d_in[17];
    const float* Ab = (const float*)d_in[18];
    const float* ew = (const float*)d_in[19];
    const float* eb = (const float*)d_in[20];
    const float* skip = (const float*)d_in[21];

    const int n0 = in_sizes[0] / NDIM;
    const int n1 = in_sizes[1] / NDIM;
    const int E0 = in_sizes[5];
    const int E1 = in_sizes[7];
    const int E2 = in_sizes[9];
    const int Emax = max(E0, max(E1, E2));
    const int cap = Emax / NRNG + 16384;            // per-range staging capacity (>50 sigma slack)
    const unsigned int magic = (unsigned int)(((8ull << 32) + (unsigned)max(n0, n1) - 1) / (unsigned)max(n0, n1));

    auto rup = [](size_t b) { return (b + 255) & ~size_t(255); };
    const size_t need =
        rup((size_t)8 * 16384 * 2) +
        rup((size_t)n0 * NDIM * 2) * 3 +
        rup((size_t)n1 * NDIM * 2) * 3 +
        rup((size_t)n1 * NDIM * 2) +
        rup((size_t)n0 * NDIM * 2) * 2 +
        rup((size_t)(n1 + 1) * 4) +
        rup((size_t)(n0 + 1) * 4) * 2 +
        rup((size_t)(n1 + n0 + n0 + 64) * 4) +
        rup((size_t)3 * MAXNB * 4) +
        rup((size_t)3 * UNITS * NRNG * 4) +
        rup((size_t)3 * NRNG * cap * 8) +
        rup((size_t)E0 * 8) + rup((size_t)E1 * 8) + rup((size_t)E2 * 8);
    if (ws_size < need) return;

    char* p = (char*)d_ws;
    auto alloc = [&](size_t bytes) -> char* {
        char* r = p;
        p += (bytes + 255) & ~size_t(255);
        return r;
    };
    unsigned short* Wtbuf = (unsigned short*)alloc((size_t)8 * 16384 * 2);
    unsigned short* K0 = (unsigned short*)alloc((size_t)n0 * NDIM * 2);
    unsigned short* Q0 = (unsigned short*)alloc((size_t)n0 * NDIM * 2);
    unsigned short* V0 = (unsigned short*)alloc((size_t)n0 * NDIM * 2);
    unsigned short* K1 = (unsigned short*)alloc((size_t)n1 * NDIM * 2);
    unsigned short* Q1 = (unsigned short*)alloc((size_t)n1 * NDIM * 2);
    unsigned short* V1 = (unsigned short*)alloc((size_t)n1 * NDIM * 2);
    unsigned short* aggb1  = (unsigned short*)alloc((size_t)n1 * NDIM * 2);
    unsigned short* aggb0a = (unsigned short*)alloc((size_t)n0 * NDIM * 2);
    unsigned short* aggb0b = (unsigned short*)alloc((size_t)n0 * NDIM * 2);
    int* off0 = (int*)alloc((size_t)(n1 + 1) * 4);
    int* off1 = (int*)alloc((size_t)(n0 + 1) * 4);
    int* off2 = (int*)alloc((size_t)(n0 + 1) * 4);
    int* posA = (int*)alloc((size_t)(n1 + n0 + n0 + 64) * 4);   // pos0|pos1|pos2|rcur(24)
    int* pos0 = posA;
    int* pos1 = posA + n1;
    int* pos2 = posA + n1 + n0;
    int* rcur = posA + n1 + n0 + n0;
    int* partial = (int*)alloc((size_t)3 * MAXNB * 4);
    int* cnts = (int*)alloc((size_t)3 * UNITS * NRNG * 4);
    uint2* stg = (uint2*)alloc((size_t)3 * NRNG * cap * 8);
    int2* edg0 = (int2*)alloc((size_t)E0 * 8);
    int2* edg1 = (int2*)alloc((size_t)E1 * 8);
    int2* edg2 = (int2*)alloc((size_t)E2 * 8);

    dim3 blk(256);
    dim3 g0((n0 + 63) / 64), g1((n1 + 63) / 64);

    wt_prep<<<8, 256, 0, stream>>>(Kw, Qw, Vw, Aw, Wtbuf);
    gemm_kqv<<<g0, blk, 0, stream>>>(feat0, Wtbuf,             Kb,        Qb,        Vb,        K0, Q0, V0, n0);
    gemm_kqv<<<g1, blk, 0, stream>>>(feat1, Wtbuf + 4 * 16384, Kb + NDIM, Qb + NDIM, Vb + NDIM, K1, Q1, V1, n1);

    hipMemsetAsync(posA, 0, (size_t)(n1 + n0 + n0 + 64) * 4, stream);

    // phase A: deterministic bucketing (no atomics)
    bucket_count<<<dim3(NBK, 3), blk, 0, stream>>>(dst0, E0, dst1, E1, dst2, E2, magic, cnts);
    bucket_scan<<<24, blk, 0, stream>>>(cnts, rcur);
    bucket_write<<<dim3(NBK, 3), blk, 0, stream>>>(dst0, src0, ev0, E0,
                                                   dst1, src1, ev1, E1,
                                                   dst2, src2, ev2, E2,
                                                   magic, ew, eb, cnts, stg, cap);

    // phase B: XCD-pinned hist + scatter from staged
    histS<<<dim3(1024, 3), blk, 0, stream>>>(stg, cap, rcur, pos0, pos1, pos2);

    const int nmax = (n0 > n1) ? n0 : n1;
    const int nb = (nmax + SCH - 1) / SCH;
    scan_partial<<<dim3(nb, 3), blk, 0, stream>>>(pos0, n1, pos1, n0, pos2, n0, partial);
    scan_base<<<1, 64, 0, stream>>>(partial, n1, n0, n0, off0, off1, off2);
    scan_final<<<dim3(nb, 3), blk, 0, stream>>>(pos0, n1, off0, pos1, n0, off1, pos2, n0, off2, partial);

    scatterS<<<dim3(1024, 3), blk, 0, stream>>>(stg, cap, rcur, pos0, pos1, pos2, edg0, edg1, edg2);

    const int ebx = ((nmax + 1) / 2 + 3) / 4;
    edge_agg3<<<dim3(ebx, 3), blk, 0, stream>>>(
        off0, edg0, K0, Q1, V0, aggb1, n1,
        off1, edg1, K1, Q0, V1, aggb0a, n0,
        off2, edg2, K0, Q0, V0, aggb0b, n0);

    float* out = (float*)d_out;
    gemm_out2<true ><<<g0, blk, 0, stream>>>(aggb0a, aggb0b, Wtbuf + 3 * 16384, Ab,        feat0, skip, 0, out, n0);
    gemm_out2<false><<<g1, blk, 0, stream>>>(aggb1,  nullptr, Wtbuf + 7 * 16384, Ab + NDIM, feat1, skip, 1, out + (size_t)n0 * NDIM, n1);
}

// Round 13
// 540.892 us; speedup vs baseline: 7.1183x; 1.1434x over previous
//
#include <hip/hip_runtime.h>
#include <hip/hip_bf16.h>
#include <math.h>

// HEAT layer. Round 13: phase B collapsed to one per-range LDS counting-sort
// kernel (sortB) — removes histS/3 scans/scatterS + pos memset. GEMM pairs
// fused (kqv, out). 15 -> 8 dispatches. edge_agg3 unchanged (attribution).

#define NDIM 128
#define NRNG 8
#define NBK 512
#define UNITS (NBK * 4)
#define HSPAN 8192      // max dst-span per range (n <= 65536)

typedef __attribute__((ext_vector_type(8))) short short8;
typedef __attribute__((ext_vector_type(4))) float f32x4;

__device__ __forceinline__ float bf2f(unsigned short u) {
    union { unsigned int i; float f; } x; x.i = ((unsigned int)u) << 16; return x.f;
}
__device__ __forceinline__ unsigned short f2bf(float f) {
    unsigned int u = __float_as_uint(f);
    unsigned int r = (u + 0x7FFFu + ((u >> 16) & 1u)) >> 16;   // RNE
    return (unsigned short)r;
}
// exact range id: r = #{k in 1..7 : d >= ceil(k*n/8)} == floor-consistent with dbase
__device__ __forceinline__ int range_of(int d, int n) {
    int r = 0;
#pragma unroll
    for (int k = 1; k < NRNG; ++k)
        r += (d >= (int)(((long long)k * n + 7) >> 3)) ? 1 : 0;
    return r;
}

// ---------------- weight prep: 8 mats f32[k][n] -> bf16 [n][k] ----------------
__global__ void wt_prep(const float* __restrict__ Kw, const float* __restrict__ Qw,
                        const float* __restrict__ Vw, const float* __restrict__ Aw,
                        unsigned short* __restrict__ Wtbuf)
{
    const int b = blockIdx.x;        // t*4 + m
    const int t = b >> 2, m = b & 3;
    const float* src = (m == 0 ? Kw : m == 1 ? Qw : m == 2 ? Vw : Aw) + (size_t)t * 16384;
    unsigned short* dst = Wtbuf + (size_t)b * 16384;
    for (int i = threadIdx.x; i < 16384; i += blockDim.x) {
        const int k = i >> 7, nn = i & 127;
        dst[nn * 128 + k] = f2bf(src[i]);
    }
}

// ---------------- fused K/Q/V MFMA GEMM, both node types in one launch ----------------
__global__ __launch_bounds__(256) void gemm_kqv(
    const float* __restrict__ feat0, const float* __restrict__ feat1,
    const unsigned short* __restrict__ Wtbuf,
    const float* __restrict__ Kb, const float* __restrict__ Qb, const float* __restrict__ Vb,
    unsigned short* __restrict__ K0o, unsigned short* __restrict__ Q0o, unsigned short* __restrict__ V0o,
    unsigned short* __restrict__ K1o, unsigned short* __restrict__ Q1o, unsigned short* __restrict__ V1o,
    int n0, int n1, int blocks0)
{
    const int b = blockIdx.x;
    const bool t1 = (b >= blocks0);
    const float* feat = t1 ? feat1 : feat0;
    const int n = t1 ? n1 : n0;
    const int boff = t1 ? NDIM : 0;
    const unsigned short* Wt = Wtbuf + (t1 ? 4 * 16384 : 0);
    unsigned short* outs[3];
    outs[0] = t1 ? K1o : K0o; outs[1] = t1 ? Q1o : Q0o; outs[2] = t1 ? V1o : V0o;
    const float* biases[3] = {Kb + boff, Qb + boff, Vb + boff};

    const int tid = threadIdx.x;
    const int w = tid >> 6, lane = tid & 63;
    const int r16 = lane & 15, kg = lane >> 4;
    const int wrow = (t1 ? b - blocks0 : b) * 64 + w * 16;
    const int arow = min(wrow + r16, n - 1);

    short8 afr[4];
#pragma unroll
    for (int k0i = 0; k0i < 4; ++k0i) {
        const float* ap = feat + (size_t)arow * NDIM + k0i * 32 + kg * 8;
        const float4 lo = *(const float4*)ap;
        const float4 hi = *(const float4*)(ap + 4);
        short8 a;
        a[0] = (short)f2bf(lo.x); a[1] = (short)f2bf(lo.y);
        a[2] = (short)f2bf(lo.z); a[3] = (short)f2bf(lo.w);
        a[4] = (short)f2bf(hi.x); a[5] = (short)f2bf(hi.y);
        a[6] = (short)f2bf(hi.z); a[7] = (short)f2bf(hi.w);
        afr[k0i] = a;
    }
#pragma unroll
    for (int m = 0; m < 3; ++m) {
        const unsigned short* wt = Wt + (size_t)m * 16384;
        f32x4 acc[8];
#pragma unroll
        for (int c = 0; c < 8; ++c) acc[c] = (f32x4){0.f, 0.f, 0.f, 0.f};
#pragma unroll
        for (int k0i = 0; k0i < 4; ++k0i)
#pragma unroll
            for (int c = 0; c < 8; ++c) {
                const short8 bb = *(const short8*)(wt + (size_t)(16 * c + r16) * NDIM + k0i * 32 + kg * 8);
                acc[c] = __builtin_amdgcn_mfma_f32_16x16x32_bf16(afr[k0i], bb, acc[c], 0, 0, 0);
            }
#pragma unroll
        for (int c = 0; c < 8; ++c) {
            const int col = 16 * c + r16;
            const float bb = biases[m][col];
#pragma unroll
            for (int j = 0; j < 4; ++j) {
                const int row = wrow + kg * 4 + j;
                if (row < n) outs[m][(size_t)row * NDIM + col] = f2bf(acc[c][j] + bb);
            }
        }
    }
}

// ---------------- fused output MFMA GEMM, both node types ----------------
__global__ __launch_bounds__(256) void gemm_out(
    const unsigned short* __restrict__ aggb0a, const unsigned short* __restrict__ aggb0b,
    const unsigned short* __restrict__ aggb1,
    const unsigned short* __restrict__ Wtbuf, const float* __restrict__ Ab,
    const float* __restrict__ feat0, const float* __restrict__ feat1,
    const float* __restrict__ skip, float* __restrict__ out,
    int n0, int n1, int blocks0)
{
    const int b = blockIdx.x;
    const bool t1 = (b >= blocks0);
    const int n = t1 ? n1 : n0;
    const unsigned short* A1 = t1 ? aggb1 : aggb0a;
    const unsigned short* A2 = t1 ? (const unsigned short*)nullptr : aggb0b;
    const unsigned short* Wt = Wtbuf + (t1 ? 7 : 3) * 16384;
    const float* bias = Ab + (t1 ? NDIM : 0);
    const float* feat = t1 ? feat1 : feat0;
    float* C = out + (t1 ? (size_t)n0 * NDIM : 0);
    const int nid = t1 ? 1 : 0;

    const int tid = threadIdx.x;
    const int w = tid >> 6, lane = tid & 63;
    const int r16 = lane & 15, kg = lane >> 4;
    const int wrow = (t1 ? b - blocks0 : b) * 64 + w * 16;
    const int arow = min(wrow + r16, n - 1);

    short8 afr[4];
#pragma unroll
    for (int k0i = 0; k0i < 4; ++k0i) {
        short8 a = *(const short8*)(A1 + (size_t)arow * NDIM + k0i * 32 + kg * 8);
        if (!t1) {
            const short8 bb = *(const short8*)(A2 + (size_t)arow * NDIM + k0i * 32 + kg * 8);
#pragma unroll
            for (int j = 0; j < 8; ++j) {
                const float v = 0.5f * (bf2f((unsigned short)a[j]) + bf2f((unsigned short)bb[j]));
                a[j] = (short)f2bf(v);
            }
        }
        afr[k0i] = a;
    }
    f32x4 acc[8];
#pragma unroll
    for (int c = 0; c < 8; ++c) acc[c] = (f32x4){0.f, 0.f, 0.f, 0.f};
#pragma unroll
    for (int k0i = 0; k0i < 4; ++k0i)
#pragma unroll
        for (int c = 0; c < 8; ++c) {
            const short8 bb = *(const short8*)(Wt + (size_t)(16 * c + r16) * NDIM + k0i * 32 + kg * 8);
            acc[c] = __builtin_amdgcn_mfma_f32_16x16x32_bf16(afr[k0i], bb, acc[c], 0, 0, 0);
        }
    const float sk = skip[nid];
    const float alpha = 1.f / (1.f + __expf(-sk));
    const float beta = 1.f - alpha;
#pragma unroll
    for (int c = 0; c < 8; ++c) {
        const int col = 16 * c + r16;
        const float bb = bias[col];
#pragma unroll
        for (int j = 0; j < 4; ++j) {
            const int row = wrow + kg * 4 + j;
            if (row < n)
                C[(size_t)row * NDIM + col] = (acc[c][j] + bb) * alpha + feat[(size_t)row * NDIM + col] * beta;
        }
    }
}

// ---------------- phase A1: per-unit range counts (ballot, zero atomics) ----------------
__global__ __launch_bounds__(256) void bucket_count(
    const int* __restrict__ d0, int E0, const int* __restrict__ d1, int E1,
    const int* __restrict__ d2, int E2, int n0, int n1, int* __restrict__ cnts)
{
    const int seg = blockIdx.y;
    const int* dst = seg == 0 ? d0 : (seg == 1 ? d1 : d2);
    const int E = seg == 0 ? E0 : (seg == 1 ? E1 : E2);
    const int ns = seg == 0 ? n1 : n0;
    const int unit = blockIdx.x * 4 + (threadIdx.x >> 6);
    const int lane = threadIdx.x & 63;
    const int span = (E + UNITS - 1) / UNITS;
    const int b = unit * span;
    const int e = min(b + span, E);

    int run[NRNG];
#pragma unroll
    for (int r0 = 0; r0 < NRNG; ++r0) run[r0] = 0;
    for (int i0 = b; i0 < e; i0 += 64) {
        const int i = i0 + lane;
        const bool v = i < e;
        const int d = v ? dst[i] : 0;
        const unsigned int r = v ? (unsigned int)range_of(d, ns) : 0xFFu;
#pragma unroll
        for (int r0 = 0; r0 < NRNG; ++r0)
            run[r0] += __popcll(__ballot(r == (unsigned int)r0));
    }
    if (lane == 0) {
        int* c = cnts + ((size_t)seg * UNITS + unit) * NRNG;
#pragma unroll
        for (int r0 = 0; r0 < NRNG; ++r0) c[r0] = run[r0];
    }
}

// ---------------- phase A2: exclusive scan of unit counts; totals -> rcur ----------------
__global__ __launch_bounds__(256) void bucket_scan(int* __restrict__ cnts, int* __restrict__ rcur)
{
    const int seg = blockIdx.x >> 3;
    const int r = blockIdx.x & 7;
    const int t = threadIdx.x, lane = t & 63, w = t >> 6;

    int v[8];
    int run = 0;
#pragma unroll
    for (int j = 0; j < 8; ++j) {
        const int u = t * 8 + j;
        const int x = cnts[((size_t)seg * UNITS + u) * NRNG + r];
        v[j] = run;
        run += x;
    }
    const int tsum = run;
    int x = tsum;
#pragma unroll
    for (int o = 1; o < 64; o <<= 1) {
        const int y = __shfl_up(x, o);
        if (lane >= o) x += y;
    }
    const int wexc = x - tsum;
    __shared__ int wsum[4];
    if (lane == 63) wsum[w] = x;
    __syncthreads();
    int wbase = 0;
    for (int i = 0; i < w; ++i) wbase += wsum[i];
    const int base = wbase + wexc;
#pragma unroll
    for (int j = 0; j < 8; ++j) {
        const int u = t * 8 + j;
        cnts[((size_t)seg * UNITS + u) * NRNG + r] = base + v[j];
    }
    if (t == 255) rcur[seg * NRNG + r] = base + tsum;
}

// ---------------- phase A3: deterministic staged write ----------------
__global__ __launch_bounds__(256) void bucket_write(
    const int* __restrict__ d0, const int* __restrict__ s0, const float* __restrict__ e0, int E0,
    const int* __restrict__ d1, const int* __restrict__ s1, const float* __restrict__ e1, int E1,
    const int* __restrict__ d2, const int* __restrict__ s2, const float* __restrict__ e2, int E2,
    int n0, int n1, const float* __restrict__ ew, const float* __restrict__ eb,
    const int* __restrict__ cnts, uint2* __restrict__ stg, int cap)
{
    const int seg = blockIdx.y;
    const int* dst = seg == 0 ? d0 : (seg == 1 ? d1 : d2);
    const int* src = seg == 0 ? s0 : (seg == 1 ? s1 : s2);
    const float* ev = seg == 0 ? e0 : (seg == 1 ? e1 : e2);
    const int E = seg == 0 ? E0 : (seg == 1 ? E1 : E2);
    const int ns = seg == 0 ? n1 : n0;
    const int unit = blockIdx.x * 4 + (threadIdx.x >> 6);
    const int lane = threadIdx.x & 63;
    const int span = (E + UNITS - 1) / UNITS;
    const int b = unit * span;
    const int e = min(b + span, E);
    const float LOG2E = 1.4426950408889634f;
    const float ews = ew[0] * 0.25f * LOG2E;
    const float ebs = eb[0] * 0.25f * LOG2E;
    uint2* sbase = stg + (size_t)seg * NRNG * cap;

    int run[NRNG];
    {
        const int* c = cnts + ((size_t)seg * UNITS + unit) * NRNG;
#pragma unroll
        for (int r0 = 0; r0 < NRNG; ++r0) run[r0] = c[r0];
    }
    for (int i0 = b; i0 < e; i0 += 64) {
        const int i = i0 + lane;
        const bool v = i < e;
        int d = 0, s = 0; float ee = 0.f;
        if (v) { d = dst[i]; s = src[i]; ee = ev[i]; }
        const unsigned int r = v ? (unsigned int)range_of(d, ns) : 0xFFu;
#pragma unroll
        for (int r0 = 0; r0 < NRNG; ++r0) {
            const unsigned long long m = __ballot(r == (unsigned int)r0);
            if (m == 0ull) continue;
            if (r == (unsigned int)r0) {
                const int off = run[r0] + __popcll(m & ((1ull << lane) - 1ull));
                sbase[(size_t)r0 * cap + off] =
                    make_uint2((unsigned int)d | ((unsigned int)s << 16), __float_as_uint(ee * ews + ebs));
            }
            run[r0] += __popcll(m);
        }
    }
}

// ---------------- phase B: per-range LDS counting sort -> off[] + edg[] ----------------
__global__ __launch_bounds__(1024) void sortB(
    const uint2* __restrict__ stg, int cap, const int* __restrict__ rcur,
    int nA, int* __restrict__ offA, int2* __restrict__ gA,
    int nB, int* __restrict__ offB, int2* __restrict__ gB,
    int nC, int* __restrict__ offC, int2* __restrict__ gC)
{
    const int seg = blockIdx.y;
    const int r = blockIdx.x;                       // 0..7
    const int n = seg == 0 ? nA : (seg == 1 ? nB : nC);
    int* off = seg == 0 ? offA : (seg == 1 ? offB : offC);
    int2* edg = seg == 0 ? gA : (seg == 1 ? gB : gC);
    const int cnt = rcur[seg * NRNG + r];
    const uint2* s = stg + ((size_t)seg * NRNG + r) * cap;
    const int dbase = (int)(((long long)r * n + 7) >> 3);        // ceil(r*n/8)
    const int dnext = (int)(((long long)(r + 1) * n + 7) >> 3);
    const int span = dnext - dbase;
    int ebase = 0;
    for (int i = 0; i < r; ++i) ebase += rcur[seg * NRNG + i];

    __shared__ int hist[HSPAN];
    __shared__ int wsum[16];
    const int tid = threadIdx.x, lane = tid & 63, wid = tid >> 6;

    for (int i = tid; i < span; i += 1024) hist[i] = 0;
    __syncthreads();
    // pass 1: histogram
    for (int i = tid; i < cnt; i += 1024)
        atomicAdd(&hist[(int)(s[i].x & 0xFFFFu) - dbase], 1);
    __syncthreads();
    // in-place exclusive block scan (+ebase) over span bins
    const int C = (span + 1023) >> 10;              // <= 8
    int v[8];
    int run = 0;
    const int b0 = tid * C;
#pragma unroll 8
    for (int j = 0; j < C; ++j) {
        const int i = b0 + j;
        const int x = (i < span) ? hist[i] : 0;
        v[j] = run;
        run += x;
    }
    int x = run;
#pragma unroll
    for (int o = 1; o < 64; o <<= 1) {
        const int y = __shfl_up(x, o);
        if (lane >= o) x += y;
    }
    if (lane == 63) wsum[wid] = x;
    __syncthreads();
    int wbase = 0;
    for (int i = 0; i < wid; ++i) wbase += wsum[i];
    const int tb = ebase + wbase + (x - run);
#pragma unroll 8
    for (int j = 0; j < C; ++j) {
        const int i = b0 + j;
        if (i < span) hist[i] = tb + v[j];
    }
    __syncthreads();
    // write CSR offsets
    for (int i = tid; i < span; i += 1024) off[dbase + i] = hist[i];
    if (r == NRNG - 1 && tid == 0) off[n] = ebase + cnt;
    __syncthreads();
    // pass 2: scatter via LDS cursors
    for (int i = tid; i < cnt; i += 1024) {
        const uint2 e = s[i];
        const int d = (int)(e.x & 0xFFFFu);
        const int p = atomicAdd(&hist[d - dbase], 1);
        edg[p] = make_int2((int)(e.x >> 16), (int)e.y);
    }
}

// ---------------- edge aggregation v3 (unchanged) ----------------
__global__ __launch_bounds__(256) void edge_agg3(
    const int* __restrict__ off0, const int2* __restrict__ edg0,
    const unsigned short* __restrict__ K0e, const unsigned short* __restrict__ Q0e,
    const unsigned short* __restrict__ V0e, unsigned short* __restrict__ out0, int nd0,
    const int* __restrict__ off1, const int2* __restrict__ edg1,
    const unsigned short* __restrict__ K1e, const unsigned short* __restrict__ Q1e,
    const unsigned short* __restrict__ V1e, unsigned short* __restrict__ out1, int nd1,
    const int* __restrict__ off2, const int2* __restrict__ edg2,
    const unsigned short* __restrict__ K2e, const unsigned short* __restrict__ Q2e,
    const unsigned short* __restrict__ V2e, unsigned short* __restrict__ out2, int nd2)
{
    const int seg = blockIdx.y;
    const int* off = seg == 0 ? off0 : (seg == 1 ? off1 : off2);
    const int2* edg = seg == 0 ? edg0 : (seg == 1 ? edg1 : edg2);
    const unsigned short* K = seg == 0 ? K0e : (seg == 1 ? K1e : K2e);
    const unsigned short* Q = seg == 0 ? Q0e : (seg == 1 ? Q1e : Q2e);
    const unsigned short* V = seg == 0 ? V0e : (seg == 1 ? V1e : V2e);
    unsigned short* aggb = seg == 0 ? out0 : (seg == 1 ? out1 : out2);
    const int n_dst = seg == 0 ? nd0 : (seg == 1 ? nd1 : nd2);

    const int wv = (blockIdx.x * blockDim.x + threadIdx.x) >> 6;
    const int lane = threadIdx.x & 63;
    const int half = lane >> 5, l5 = lane & 31;
    const int dst = 2 * wv + half;
    const bool valid = dst < n_dst;
    int beg = 0, len = 0;
    if (valid) { beg = off[dst]; len = off[dst + 1] - beg; }
    const int maxLen = max(len, __shfl_xor(len, 32));
    if (maxLen == 0) {
        if (valid) *(ushort4*)(aggb + (size_t)dst * NDIM + 4 * l5) = (ushort4){0, 0, 0, 0};
        return;
    }
    float qx = 0.f, qy = 0.f, qz = 0.f, qw = 0.f;
    if (valid) {
        const ushort4 qr = *(const ushort4*)(Q + (size_t)dst * NDIM + 4 * l5);
        qx = bf2f(qr.x); qy = bf2f(qr.y); qz = bf2f(qr.z); qw = bf2f(qr.w);
    }
    float z = 0.f, a0 = 0.f, a1 = 0.f, a2 = 0.f, a3 = 0.f;

    int2 ec = (l5 < len) ? edg[beg + l5] : make_int2(0, 0);
    for (int t0 = 0; t0 < maxLen; t0 += 32) {
        int2 en = make_int2(0, 0);
        const int t0n = t0 + 32;
        if (t0n < maxLen && t0n + l5 < len) en = edg[beg + t0n + l5];
        const int lim = min(32, maxLen - t0);
        for (int u = 0; u < lim; ++u) {
            const int sl = (half << 5) + u;
            const int s = __shfl(ec.x, sl);
            const float w = __int_as_float(__shfl(ec.y, sl));
            const bool act = (t0 + u) < len;
            const ushort4 kr = *(const ushort4*)(K + (size_t)s * NDIM + 4 * l5);
            const ushort4 vr = *(const ushort4*)(V + (size_t)s * NDIM + 4 * l5);
            float d = qx * bf2f(kr.x) + qy * bf2f(kr.y) + qz * bf2f(kr.z) + qw * bf2f(kr.w);
            d += __shfl_xor(d, 1);
            d += __shfl_xor(d, 2);
            const float p = act ? exp2f(d * w) : 0.f;           // no-max softmax
            z += p;
            a0 += p * bf2f(vr.x);
            a1 += p * bf2f(vr.y);
            a2 += p * bf2f(vr.z);
            a3 += p * bf2f(vr.w);
        }
        ec = en;
    }
    if (valid) {
        const float inv = (len > 0) ? 1.f / z : 0.f;
        ushort4 o;
        o.x = f2bf(a0 * inv); o.y = f2bf(a1 * inv);
        o.z = f2bf(a2 * inv); o.w = f2bf(a3 * inv);
        *(ushort4*)(aggb + (size_t)dst * NDIM + 4 * l5) = o;
    }
}

extern "C" void kernel_launch(void* const* d_in, const int* in_sizes, int n_in,
                              void* d_out, int out_size, void* d_ws, size_t ws_size,
                              hipStream_t stream)
{
    const float* feat0 = (const float*)d_in[0];
    const float* feat1 = (const float*)d_in[1];
    const float* ev0 = (const float*)d_in[2];
    const float* ev1 = (const float*)d_in[3];
    const float* ev2 = (const float*)d_in[4];
    const int* src0 = (const int*)d_in[5];
    const int* dst0 = (const int*)d_in[6];
    const int* src1 = (const int*)d_in[7];
    const int* dst1 = (const int*)d_in[8];
    const int* src2 = (const int*)d_in[9];
    const int* dst2 = (const int*)d_in[10];
    const float* Kw = (const float*)d_in[11];
    const float* Kb = (const float*)d_in[12];
    const float* Qw = (const float*)d_in[13];
    const float* Qb = (const float*)d_in[14];
    const float* Vw = (const float*)d_in[15];
    const float* Vb = (const float*)d_in[16];
    const float* Aw = (const float*)d_in[17];
    const float* Ab = (const float*)d_in[18];
    const float* ew = (const float*)d_in[19];
    const float* eb = (const float*)d_in[20];
    const float* skip = (const float*)d_in[21];

    const int n0 = in_sizes[0] / NDIM;
    const int n1 = in_sizes[1] / NDIM;
    const int E0 = in_sizes[5];
    const int E1 = in_sizes[7];
    const int E2 = in_sizes[9];
    if (max(n0, n1) > 8 * HSPAN - 8) return;        // sortB span guard
    const int Emax = max(E0, max(E1, E2));
    const int cap = Emax / NRNG + 16384;

    auto rup = [](size_t b) { return (b + 255) & ~size_t(255); };
    const size_t need =
        rup((size_t)8 * 16384 * 2) +
        rup((size_t)n0 * NDIM * 2) * 3 +
        rup((size_t)n1 * NDIM * 2) * 3 +
        rup((size_t)n1 * NDIM * 2) +
        rup((size_t)n0 * NDIM * 2) * 2 +
        rup((size_t)(n1 + 1) * 4) +
        rup((size_t)(n0 + 1) * 4) * 2 +
        rup((size_t)64 * 4) +
        rup((size_t)3 * UNITS * NRNG * 4) +
        rup((size_t)3 * NRNG * cap * 8) +
        rup((size_t)E0 * 8) + rup((size_t)E1 * 8) + rup((size_t)E2 * 8);
    if (ws_size < need) return;

    char* p = (char*)d_ws;
    auto alloc = [&](size_t bytes) -> char* {
        char* r = p;
        p += (bytes + 255) & ~size_t(255);
        return r;
    };
    unsigned short* Wtbuf = (unsigned short*)alloc((size_t)8 * 16384 * 2);
    unsigned short* K0 = (unsigned short*)alloc((size_t)n0 * NDIM * 2);
    unsigned short* Q0 = (unsigned short*)alloc((size_t)n0 * NDIM * 2);
    unsigned short* V0 = (unsigned short*)alloc((size_t)n0 * NDIM * 2);
    unsigned short* K1 = (unsigned short*)alloc((size_t)n1 * NDIM * 2);
    unsigned short* Q1 = (unsigned short*)alloc((size_t)n1 * NDIM * 2);
    unsigned short* V1 = (unsigned short*)alloc((size_t)n1 * NDIM * 2);
    unsigned short* aggb1  = (unsigned short*)alloc((size_t)n1 * NDIM * 2);
    unsigned short* aggb0a = (unsigned short*)alloc((size_t)n0 * NDIM * 2);
    unsigned short* aggb0b = (unsigned short*)alloc((size_t)n0 * NDIM * 2);
    int* off0 = (int*)alloc((size_t)(n1 + 1) * 4);
    int* off1 = (int*)alloc((size_t)(n0 + 1) * 4);
    int* off2 = (int*)alloc((size_t)(n0 + 1) * 4);
    int* rcur = (int*)alloc((size_t)64 * 4);
    int* cnts = (int*)alloc((size_t)3 * UNITS * NRNG * 4);
    uint2* stg = (uint2*)alloc((size_t)3 * NRNG * cap * 8);
    int2* edg0 = (int2*)alloc((size_t)E0 * 8);
    int2* edg1 = (int2*)alloc((size_t)E1 * 8);
    int2* edg2 = (int2*)alloc((size_t)E2 * 8);

    dim3 blk(256);
    const int blocks0 = (n0 + 63) / 64, blocks1 = (n1 + 63) / 64;

    wt_prep<<<8, 256, 0, stream>>>(Kw, Qw, Vw, Aw, Wtbuf);
    gemm_kqv<<<blocks0 + blocks1, blk, 0, stream>>>(feat0, feat1, Wtbuf, Kb, Qb, Vb,
                                                    K0, Q0, V0, K1, Q1, V1, n0, n1, blocks0);

    bucket_count<<<dim3(NBK, 3), blk, 0, stream>>>(dst0, E0, dst1, E1, dst2, E2, n0, n1, cnts);
    bucket_scan<<<24, blk, 0, stream>>>(cnts, rcur);
    bucket_write<<<dim3(NBK, 3), blk, 0, stream>>>(dst0, src0, ev0, E0,
                                                   dst1, src1, ev1, E1,
                                                   dst2, src2, ev2, E2,
                                                   n0, n1, ew, eb, cnts, stg, cap);
    sortB<<<dim3(NRNG, 3), 1024, 0, stream>>>(stg, cap, rcur,
                                              n1, off0, edg0,
                                              n0, off1, edg1,
                                              n0, off2, edg2);

    const int nmax = (n0 > n1) ? n0 : n1;
    const int ebx = ((nmax + 1) / 2 + 3) / 4;
    edge_agg3<<<dim3(ebx, 3), blk, 0, stream>>>(
        off0, edg0, K0, Q1, V0, aggb1, n1,
        off1, edg1, K1, Q0, V1, aggb0a, n0,
        off2, edg2, K0, Q0, V0, aggb0b, n0);

    gemm_out<<<blocks0 + blocks1, blk, 0, stream>>>(aggb0a, aggb0b, aggb1, Wtbuf, Ab,
                                                    feat0, feat1, skip, (float*)d_out,
                                                    n0, n1, blocks0);
}

// Round 14
// 451.135 us; speedup vs baseline: 8.5346x; 1.1990x over previous
//
#include <hip/hip_runtime.h>
#include <hip/hip_bf16.h>
#include <hip/hip_fp16.h>
#include <math.h>

// HEAT layer. Round 14: NRNG 8->32 (sortB 24->96 blocks, the r13 serialization),
// u32 edge payload (src | fp16(w)<<16, halves sort scatter + agg edge stream),
// div-based exact range id. edge_agg3 / MFMA GEMMs otherwise unchanged.

#define NDIM 128
#define NRNG 32
#define NBK 512
#define UNITS (NBK * 4)
#define HSPAN 2048      // max dst-span per range (n <= 65504)

typedef __attribute__((ext_vector_type(8))) short short8;
typedef __attribute__((ext_vector_type(4))) float f32x4;

__device__ __forceinline__ float bf2f(unsigned short u) {
    union { unsigned int i; float f; } x; x.i = ((unsigned int)u) << 16; return x.f;
}
__device__ __forceinline__ unsigned short f2bf(float f) {
    unsigned int u = __float_as_uint(f);
    unsigned int r = (u + 0x7FFFu + ((u >> 16) & 1u)) >> 16;   // RNE
    return (unsigned short)r;
}
// exact range id, consistent with dbase = ceil(r*n/NRNG)
__device__ __forceinline__ int range_of(int d, int n) {
    return (int)(((long long)d * NRNG) / n);
}

// ---------------- weight prep: 8 mats f32[k][n] -> bf16 [n][k] ----------------
__global__ void wt_prep(const float* __restrict__ Kw, const float* __restrict__ Qw,
                        const float* __restrict__ Vw, const float* __restrict__ Aw,
                        unsigned short* __restrict__ Wtbuf)
{
    const int b = blockIdx.x;        // t*4 + m
    const int t = b >> 2, m = b & 3;
    const float* src = (m == 0 ? Kw : m == 1 ? Qw : m == 2 ? Vw : Aw) + (size_t)t * 16384;
    unsigned short* dst = Wtbuf + (size_t)b * 16384;
    for (int i = threadIdx.x; i < 16384; i += blockDim.x) {
        const int k = i >> 7, nn = i & 127;
        dst[nn * 128 + k] = f2bf(src[i]);
    }
}

// ---------------- fused K/Q/V MFMA GEMM, both node types in one launch ----------------
__global__ __launch_bounds__(256) void gemm_kqv(
    const float* __restrict__ feat0, const float* __restrict__ feat1,
    const unsigned short* __restrict__ Wtbuf,
    const float* __restrict__ Kb, const float* __restrict__ Qb, const float* __restrict__ Vb,
    unsigned short* __restrict__ K0o, unsigned short* __restrict__ Q0o, unsigned short* __restrict__ V0o,
    unsigned short* __restrict__ K1o, unsigned short* __restrict__ Q1o, unsigned short* __restrict__ V1o,
    int n0, int n1, int blocks0)
{
    const int b = blockIdx.x;
    const bool t1 = (b >= blocks0);
    const float* feat = t1 ? feat1 : feat0;
    const int n = t1 ? n1 : n0;
    const int boff = t1 ? NDIM : 0;
    const unsigned short* Wt = Wtbuf + (t1 ? 4 * 16384 : 0);
    unsigned short* outs[3];
    outs[0] = t1 ? K1o : K0o; outs[1] = t1 ? Q1o : Q0o; outs[2] = t1 ? V1o : V0o;
    const float* biases[3] = {Kb + boff, Qb + boff, Vb + boff};

    const int tid = threadIdx.x;
    const int w = tid >> 6, lane = tid & 63;
    const int r16 = lane & 15, kg = lane >> 4;
    const int wrow = (t1 ? b - blocks0 : b) * 64 + w * 16;
    const int arow = min(wrow + r16, n - 1);

    short8 afr[4];
#pragma unroll
    for (int k0i = 0; k0i < 4; ++k0i) {
        const float* ap = feat + (size_t)arow * NDIM + k0i * 32 + kg * 8;
        const float4 lo = *(const float4*)ap;
        const float4 hi = *(const float4*)(ap + 4);
        short8 a;
        a[0] = (short)f2bf(lo.x); a[1] = (short)f2bf(lo.y);
        a[2] = (short)f2bf(lo.z); a[3] = (short)f2bf(lo.w);
        a[4] = (short)f2bf(hi.x); a[5] = (short)f2bf(hi.y);
        a[6] = (short)f2bf(hi.z); a[7] = (short)f2bf(hi.w);
        afr[k0i] = a;
    }
#pragma unroll
    for (int m = 0; m < 3; ++m) {
        const unsigned short* wt = Wt + (size_t)m * 16384;
        f32x4 acc[8];
#pragma unroll
        for (int c = 0; c < 8; ++c) acc[c] = (f32x4){0.f, 0.f, 0.f, 0.f};
#pragma unroll
        for (int k0i = 0; k0i < 4; ++k0i)
#pragma unroll
            for (int c = 0; c < 8; ++c) {
                const short8 bb = *(const short8*)(wt + (size_t)(16 * c + r16) * NDIM + k0i * 32 + kg * 8);
                acc[c] = __builtin_amdgcn_mfma_f32_16x16x32_bf16(afr[k0i], bb, acc[c], 0, 0, 0);
            }
#pragma unroll
        for (int c = 0; c < 8; ++c) {
            const int col = 16 * c + r16;
            const float bb = biases[m][col];
#pragma unroll
            for (int j = 0; j < 4; ++j) {
                const int row = wrow + kg * 4 + j;
                if (row < n) outs[m][(size_t)row * NDIM + col] = f2bf(acc[c][j] + bb);
            }
        }
    }
}

// ---------------- fused output MFMA GEMM, both node types ----------------
__global__ __launch_bounds__(256) void gemm_out(
    const unsigned short* __restrict__ aggb0a, const unsigned short* __restrict__ aggb0b,
    const unsigned short* __restrict__ aggb1,
    const unsigned short* __restrict__ Wtbuf, const float* __restrict__ Ab,
    const float* __restrict__ feat0, const float* __restrict__ feat1,
    const float* __restrict__ skip, float* __restrict__ out,
    int n0, int n1, int blocks0)
{
    const int b = blockIdx.x;
    const bool t1 = (b >= blocks0);
    const int n = t1 ? n1 : n0;
    const unsigned short* A1 = t1 ? aggb1 : aggb0a;
    const unsigned short* A2 = t1 ? (const unsigned short*)nullptr : aggb0b;
    const unsigned short* Wt = Wtbuf + (t1 ? 7 : 3) * 16384;
    const float* bias = Ab + (t1 ? NDIM : 0);
    const float* feat = t1 ? feat1 : feat0;
    float* C = out + (t1 ? (size_t)n0 * NDIM : 0);
    const int nid = t1 ? 1 : 0;

    const int tid = threadIdx.x;
    const int w = tid >> 6, lane = tid & 63;
    const int r16 = lane & 15, kg = lane >> 4;
    const int wrow = (t1 ? b - blocks0 : b) * 64 + w * 16;
    const int arow = min(wrow + r16, n - 1);

    short8 afr[4];
#pragma unroll
    for (int k0i = 0; k0i < 4; ++k0i) {
        short8 a = *(const short8*)(A1 + (size_t)arow * NDIM + k0i * 32 + kg * 8);
        if (!t1) {
            const short8 bb = *(const short8*)(A2 + (size_t)arow * NDIM + k0i * 32 + kg * 8);
#pragma unroll
            for (int j = 0; j < 8; ++j) {
                const float v = 0.5f * (bf2f((unsigned short)a[j]) + bf2f((unsigned short)bb[j]));
                a[j] = (short)f2bf(v);
            }
        }
        afr[k0i] = a;
    }
    f32x4 acc[8];
#pragma unroll
    for (int c = 0; c < 8; ++c) acc[c] = (f32x4){0.f, 0.f, 0.f, 0.f};
#pragma unroll
    for (int k0i = 0; k0i < 4; ++k0i)
#pragma unroll
        for (int c = 0; c < 8; ++c) {
            const short8 bb = *(const short8*)(Wt + (size_t)(16 * c + r16) * NDIM + k0i * 32 + kg * 8);
            acc[c] = __builtin_amdgcn_mfma_f32_16x16x32_bf16(afr[k0i], bb, acc[c], 0, 0, 0);
        }
    const float sk = skip[nid];
    const float alpha = 1.f / (1.f + __expf(-sk));
    const float beta = 1.f - alpha;
#pragma unroll
    for (int c = 0; c < 8; ++c) {
        const int col = 16 * c + r16;
        const float bb = bias[col];
#pragma unroll
        for (int j = 0; j < 4; ++j) {
            const int row = wrow + kg * 4 + j;
            if (row < n)
                C[(size_t)row * NDIM + col] = (acc[c][j] + bb) * alpha + feat[(size_t)row * NDIM + col] * beta;
        }
    }
}

// ---------------- phase A1: per-unit range counts (ballot, zero atomics) ----------------
__global__ __launch_bounds__(256) void bucket_count(
    const int* __restrict__ d0, int E0, const int* __restrict__ d1, int E1,
    const int* __restrict__ d2, int E2, int n0, int n1, int* __restrict__ cnts)
{
    const int seg = blockIdx.y;
    const int* dst = seg == 0 ? d0 : (seg == 1 ? d1 : d2);
    const int E = seg == 0 ? E0 : (seg == 1 ? E1 : E2);
    const int ns = seg == 0 ? n1 : n0;
    const int unit = blockIdx.x * 4 + (threadIdx.x >> 6);
    const int lane = threadIdx.x & 63;
    const int span = (E + UNITS - 1) / UNITS;
    const int b = unit * span;
    const int e = min(b + span, E);

    int run[NRNG];
#pragma unroll
    for (int r0 = 0; r0 < NRNG; ++r0) run[r0] = 0;
    for (int i0 = b; i0 < e; i0 += 64) {
        const int i = i0 + lane;
        const bool v = i < e;
        const int d = v ? dst[i] : 0;
        const unsigned int r = v ? (unsigned int)range_of(d, ns) : 0xFFu;
#pragma unroll
        for (int r0 = 0; r0 < NRNG; ++r0)
            run[r0] += __popcll(__ballot(r == (unsigned int)r0));
    }
    if (lane == 0) {
        int* c = cnts + ((size_t)seg * UNITS + unit) * NRNG;
#pragma unroll
        for (int r0 = 0; r0 < NRNG; ++r0) c[r0] = run[r0];
    }
}

// ---------------- phase A2: exclusive scan of unit counts; totals -> rcur ----------------
__global__ __launch_bounds__(256) void bucket_scan(int* __restrict__ cnts, int* __restrict__ rcur)
{
    const int seg = blockIdx.x >> 5;
    const int r = blockIdx.x & 31;
    const int t = threadIdx.x, lane = t & 63, w = t >> 6;

    int v[8];
    int run = 0;
#pragma unroll
    for (int j = 0; j < 8; ++j) {
        const int u = t * 8 + j;
        const int x = cnts[((size_t)seg * UNITS + u) * NRNG + r];
        v[j] = run;
        run += x;
    }
    const int tsum = run;
    int x = tsum;
#pragma unroll
    for (int o = 1; o < 64; o <<= 1) {
        const int y = __shfl_up(x, o);
        if (lane >= o) x += y;
    }
    const int wexc = x - tsum;
    __shared__ int wsum[4];
    if (lane == 63) wsum[w] = x;
    __syncthreads();
    int wbase = 0;
    for (int i = 0; i < w; ++i) wbase += wsum[i];
    const int base = wbase + wexc;
#pragma unroll
    for (int j = 0; j < 8; ++j) {
        const int u = t * 8 + j;
        cnts[((size_t)seg * UNITS + u) * NRNG + r] = base + v[j];
    }
    if (t == 255) rcur[seg * NRNG + r] = base + tsum;
}

// ---------------- phase A3: deterministic staged write ----------------
__global__ __launch_bounds__(256) void bucket_write(
    const int* __restrict__ d0, const int* __restrict__ s0, const float* __restrict__ e0, int E0,
    const int* __restrict__ d1, const int* __restrict__ s1, const float* __restrict__ e1, int E1,
    const int* __restrict__ d2, const int* __restrict__ s2, const float* __restrict__ e2, int E2,
    int n0, int n1, const float* __restrict__ ew, const float* __restrict__ eb,
    const int* __restrict__ cnts, uint2* __restrict__ stg, int cap)
{
    const int seg = blockIdx.y;
    const int* dst = seg == 0 ? d0 : (seg == 1 ? d1 : d2);
    const int* src = seg == 0 ? s0 : (seg == 1 ? s1 : s2);
    const float* ev = seg == 0 ? e0 : (seg == 1 ? e1 : e2);
    const int E = seg == 0 ? E0 : (seg == 1 ? E1 : E2);
    const int ns = seg == 0 ? n1 : n0;
    const int unit = blockIdx.x * 4 + (threadIdx.x >> 6);
    const int lane = threadIdx.x & 63;
    const int span = (E + UNITS - 1) / UNITS;
    const int b = unit * span;
    const int e = min(b + span, E);
    const float LOG2E = 1.4426950408889634f;
    const float ews = ew[0] * 0.25f * LOG2E;
    const float ebs = eb[0] * 0.25f * LOG2E;
    uint2* sbase = stg + (size_t)seg * NRNG * cap;

    int run[NRNG];
    {
        const int* c = cnts + ((size_t)seg * UNITS + unit) * NRNG;
#pragma unroll
        for (int r0 = 0; r0 < NRNG; ++r0) run[r0] = c[r0];
    }
    for (int i0 = b; i0 < e; i0 += 64) {
        const int i = i0 + lane;
        const bool v = i < e;
        int d = 0, s = 0; float ee = 0.f;
        if (v) { d = dst[i]; s = src[i]; ee = ev[i]; }
        const unsigned int r = v ? (unsigned int)range_of(d, ns) : 0xFFu;
#pragma unroll
        for (int r0 = 0; r0 < NRNG; ++r0) {
            const unsigned long long m = __ballot(r == (unsigned int)r0);
            if (m == 0ull) continue;
            if (r == (unsigned int)r0) {
                const int off = run[r0] + __popcll(m & ((1ull << lane) - 1ull));
                sbase[(size_t)r0 * cap + off] =
                    make_uint2((unsigned int)d | ((unsigned int)s << 16), __float_as_uint(ee * ews + ebs));
            }
            run[r0] += __popcll(m);
        }
    }
}

// ---------------- phase B: per-range LDS counting sort -> off[] + edg[] (u32) ----------------
__global__ __launch_bounds__(1024) void sortB(
    const uint2* __restrict__ stg, int cap, const int* __restrict__ rcur,
    int nA, int* __restrict__ offA, unsigned int* __restrict__ gA,
    int nB, int* __restrict__ offB, unsigned int* __restrict__ gB,
    int nC, int* __restrict__ offC, unsigned int* __restrict__ gC)
{
    const int seg = blockIdx.y;
    const int r = blockIdx.x;                       // 0..NRNG-1
    const int n = seg == 0 ? nA : (seg == 1 ? nB : nC);
    int* off = seg == 0 ? offA : (seg == 1 ? offB : offC);
    unsigned int* edg = seg == 0 ? gA : (seg == 1 ? gB : gC);
    const int cnt = rcur[seg * NRNG + r];
    const uint2* s = stg + ((size_t)seg * NRNG + r) * cap;
    const int dbase = (int)(((long long)r * n + NRNG - 1) / NRNG);        // ceil(r*n/NRNG)
    const int dnext = (int)(((long long)(r + 1) * n + NRNG - 1) / NRNG);
    const int span = dnext - dbase;
    int ebase = 0;
    for (int i = 0; i < r; ++i) ebase += rcur[seg * NRNG + i];

    __shared__ int hist[HSPAN];
    __shared__ int wsum[16];
    const int tid = threadIdx.x, lane = tid & 63, wid = tid >> 6;

    for (int i = tid; i < span; i += 1024) hist[i] = 0;
    __syncthreads();
    // pass 1: histogram
    for (int i = tid; i < cnt; i += 1024)
        atomicAdd(&hist[(int)(s[i].x & 0xFFFFu) - dbase], 1);
    __syncthreads();
    // in-place exclusive block scan (+ebase) over span bins
    const int C = (span + 1023) >> 10;              // <= 2
    int v[4];
    int run = 0;
    const int b0 = tid * C;
#pragma unroll 4
    for (int j = 0; j < C; ++j) {
        const int i = b0 + j;
        const int x = (i < span) ? hist[i] : 0;
        v[j] = run;
        run += x;
    }
    int x = run;
#pragma unroll
    for (int o = 1; o < 64; o <<= 1) {
        const int y = __shfl_up(x, o);
        if (lane >= o) x += y;
    }
    if (lane == 63) wsum[wid] = x;
    __syncthreads();
    int wbase = 0;
    for (int i = 0; i < wid; ++i) wbase += wsum[i];
    const int tb = ebase + wbase + (x - run);
#pragma unroll 4
    for (int j = 0; j < C; ++j) {
        const int i = b0 + j;
        if (i < span) hist[i] = tb + v[j];
    }
    __syncthreads();
    // write CSR offsets
    for (int i = tid; i < span; i += 1024) off[dbase + i] = hist[i];
    if (r == NRNG - 1 && tid == 0) off[n] = ebase + cnt;
    __syncthreads();
    // pass 2: scatter via LDS cursors; payload = src | fp16(w)<<16
    for (int i = tid; i < cnt; i += 1024) {
        const uint2 e = s[i];
        const int d = (int)(e.x & 0xFFFFu);
        const int p = atomicAdd(&hist[d - dbase], 1);
        const float wf = __uint_as_float(e.y);
        const __half hh = __float2half(wf);
        edg[p] = (e.x >> 16) | ((unsigned int)__half_as_ushort(hh) << 16);
    }
}

// ---------------- edge aggregation v3 (u32 payload, single shfl broadcast) ----------------
__global__ __launch_bounds__(256) void edge_agg3(
    const int* __restrict__ off0, const unsigned int* __restrict__ edg0,
    const unsigned short* __restrict__ K0e, const unsigned short* __restrict__ Q0e,
    const unsigned short* __restrict__ V0e, unsigned short* __restrict__ out0, int nd0,
    const int* __restrict__ off1, const unsigned int* __restrict__ edg1,
    const unsigned short* __restrict__ K1e, const unsigned short* __restrict__ Q1e,
    const unsigned short* __restrict__ V1e, unsigned short* __restrict__ out1, int nd1,
    const int* __restrict__ off2, const unsigned int* __restrict__ edg2,
    const unsigned short* __restrict__ K2e, const unsigned short* __restrict__ Q2e,
    const unsigned short* __restrict__ V2e, unsigned short* __restrict__ out2, int nd2)
{
    const int seg = blockIdx.y;
    const int* off = seg == 0 ? off0 : (seg == 1 ? off1 : off2);
    const unsigned int* edg = seg == 0 ? edg0 : (seg == 1 ? edg1 : edg2);
    const unsigned short* K = seg == 0 ? K0e : (seg == 1 ? K1e : K2e);
    const unsigned short* Q = seg == 0 ? Q0e : (seg == 1 ? Q1e : Q2e);
    const unsigned short* V = seg == 0 ? V0e : (seg == 1 ? V1e : V2e);
    unsigned short* aggb = seg == 0 ? out0 : (seg == 1 ? out1 : out2);
    const int n_dst = seg == 0 ? nd0 : (seg == 1 ? nd1 : nd2);

    const int wv = (blockIdx.x * blockDim.x + threadIdx.x) >> 6;
    const int lane = threadIdx.x & 63;
    const int half = lane >> 5, l5 = lane & 31;
    const int dst = 2 * wv + half;
    const bool valid = dst < n_dst;
    int beg = 0, len = 0;
    if (valid) { beg = off[dst]; len = off[dst + 1] - beg; }
    const int maxLen = max(len, __shfl_xor(len, 32));
    if (maxLen == 0) {
        if (valid) *(ushort4*)(aggb + (size_t)dst * NDIM + 4 * l5) = (ushort4){0, 0, 0, 0};
        return;
    }
    float qx = 0.f, qy = 0.f, qz = 0.f, qw = 0.f;
    if (valid) {
        const ushort4 qr = *(const ushort4*)(Q + (size_t)dst * NDIM + 4 * l5);
        qx = bf2f(qr.x); qy = bf2f(qr.y); qz = bf2f(qr.z); qw = bf2f(qr.w);
    }
    float z = 0.f, a0 = 0.f, a1 = 0.f, a2 = 0.f, a3 = 0.f;

    unsigned int ec = (l5 < len) ? edg[beg + l5] : 0u;
    for (int t0 = 0; t0 < maxLen; t0 += 32) {
        unsigned int en = 0u;
        const int t0n = t0 + 32;
        if (t0n < maxLen && t0n + l5 < len) en = edg[beg + t0n + l5];
        const int lim = min(32, maxLen - t0);
        for (int u = 0; u < lim; ++u) {
            const int sl = (half << 5) + u;
            const unsigned int vv = (unsigned int)__shfl((int)ec, sl);
            const int s = (int)(vv & 0xFFFFu);
            const float w = __half2float(__ushort_as_half((unsigned short)(vv >> 16)));
            const bool act = (t0 + u) < len;
            const ushort4 kr = *(const ushort4*)(K + (size_t)s * NDIM + 4 * l5);
            const ushort4 vr = *(const ushort4*)(V + (size_t)s * NDIM + 4 * l5);
            float d = qx * bf2f(kr.x) + qy * bf2f(kr.y) + qz * bf2f(kr.z) + qw * bf2f(kr.w);
            d += __shfl_xor(d, 1);
            d += __shfl_xor(d, 2);
            const float p = act ? exp2f(d * w) : 0.f;           // no-max softmax
            z += p;
            a0 += p * bf2f(vr.x);
            a1 += p * bf2f(vr.y);
            a2 += p * bf2f(vr.z);
            a3 += p * bf2f(vr.w);
        }
        ec = en;
    }
    if (valid) {
        const float inv = (len > 0) ? 1.f / z : 0.f;
        ushort4 o;
        o.x = f2bf(a0 * inv); o.y = f2bf(a1 * inv);
        o.z = f2bf(a2 * inv); o.w = f2bf(a3 * inv);
        *(ushort4*)(aggb + (size_t)dst * NDIM + 4 * l5) = o;
    }
}

extern "C" void kernel_launch(void* const* d_in, const int* in_sizes, int n_in,
                              void* d_out, int out_size, void* d_ws, size_t ws_size,
                              hipStream_t stream)
{
    const float* feat0 = (const float*)d_in[0];
    const float* feat1 = (const float*)d_in[1];
    const float* ev0 = (const float*)d_in[2];
    const float* ev1 = (const float*)d_in[3];
    const float* ev2 = (const float*)d_in[4];
    const int* src0 = (const int*)d_in[5];
    const int* dst0 = (const int*)d_in[6];
    const int* src1 = (const int*)d_in[7];
    const int* dst1 = (const int*)d_in[8];
    const int* src2 = (const int*)d_in[9];
    const int* dst2 = (const int*)d_in[10];
    const float* Kw = (const float*)d_in[11];
    const float* Kb = (const float*)d_in[12];
    const float* Qw = (const float*)d_in[13];
    const float* Qb = (const float*)d_in[14];
    const float* Vw = (const float*)d_in[15];
    const float* Vb = (const float*)d_in[16];
    const float* Aw = (const float*)d_in[17];
    const float* Ab = (const float*)d_in[18];
    const float* ew = (const float*)d_in[19];
    const float* eb = (const float*)d_in[20];
    const float* skip = (const float*)d_in[21];

    const int n0 = in_sizes[0] / NDIM;
    const int n1 = in_sizes[1] / NDIM;
    const int E0 = in_sizes[5];
    const int E1 = in_sizes[7];
    const int E2 = in_sizes[9];
    if (max(n0, n1) > 65504) return;                // u16 packing + span guard
    const int Emax = max(E0, max(E1, E2));
    const int cap = Emax / NRNG + 8192;

    auto rup = [](size_t b) { return (b + 255) & ~size_t(255); };
    const size_t need =
        rup((size_t)8 * 16384 * 2) +
        rup((size_t)n0 * NDIM * 2) * 3 +
        rup((size_t)n1 * NDIM * 2) * 3 +
        rup((size_t)n1 * NDIM * 2) +
        rup((size_t)n0 * NDIM * 2) * 2 +
        rup((size_t)(n1 + 1) * 4) +
        rup((size_t)(n0 + 1) * 4) * 2 +
        rup((size_t)128 * 4) +
        rup((size_t)3 * UNITS * NRNG * 4) +
        rup((size_t)3 * NRNG * cap * 8) +
        rup((size_t)E0 * 4) + rup((size_t)E1 * 4) + rup((size_t)E2 * 4);
    if (ws_size < need) return;

    char* p = (char*)d_ws;
    auto alloc = [&](size_t bytes) -> char* {
        char* r = p;
        p += (bytes + 255) & ~size_t(255);
        return r;
    };
    unsigned short* Wtbuf = (unsigned short*)alloc((size_t)8 * 16384 * 2);
    unsigned short* K0 = (unsigned short*)alloc((size_t)n0 * NDIM * 2);
    unsigned short* Q0 = (unsigned short*)alloc((size_t)n0 * NDIM * 2);
    unsigned short* V0 = (unsigned short*)alloc((size_t)n0 * NDIM * 2);
    unsigned short* K1 = (unsigned short*)alloc((size_t)n1 * NDIM * 2);
    unsigned short* Q1 = (unsigned short*)alloc((size_t)n1 * NDIM * 2);
    unsigned short* V1 = (unsigned short*)alloc((size_t)n1 * NDIM * 2);
    unsigned short* aggb1  = (unsigned short*)alloc((size_t)n1 * NDIM * 2);
    unsigned short* aggb0a = (unsigned short*)alloc((size_t)n0 * NDIM * 2);
    unsigned short* aggb0b = (unsigned short*)alloc((size_t)n0 * NDIM * 2);
    int* off0 = (int*)alloc((size_t)(n1 + 1) * 4);
    int* off1 = (int*)alloc((size_t)(n0 + 1) * 4);
    int* off2 = (int*)alloc((size_t)(n0 + 1) * 4);
    int* rcur = (int*)alloc((size_t)128 * 4);
    int* cnts = (int*)alloc((size_t)3 * UNITS * NRNG * 4);
    uint2* stg = (uint2*)alloc((size_t)3 * NRNG * cap * 8);
    unsigned int* edg0 = (unsigned int*)alloc((size_t)E0 * 4);
    unsigned int* edg1 = (unsigned int*)alloc((size_t)E1 * 4);
    unsigned int* edg2 = (unsigned int*)alloc((size_t)E2 * 4);

    dim3 blk(256);
    const int blocks0 = (n0 + 63) / 64, blocks1 = (n1 + 63) / 64;

    wt_prep<<<8, 256, 0, stream>>>(Kw, Qw, Vw, Aw, Wtbuf);
    gemm_kqv<<<blocks0 + blocks1, blk, 0, stream>>>(feat0, feat1, Wtbuf, Kb, Qb, Vb,
                                                    K0, Q0, V0, K1, Q1, V1, n0, n1, blocks0);

    bucket_count<<<dim3(NBK, 3), blk, 0, stream>>>(dst0, E0, dst1, E1, dst2, E2, n0, n1, cnts);
    bucket_scan<<<3 * NRNG, blk, 0, stream>>>(cnts, rcur);
    bucket_write<<<dim3(NBK, 3), blk, 0, stream>>>(dst0, src0, ev0, E0,
                                                   dst1, src1, ev1, E1,
                                                   dst2, src2, ev2, E2,
                                                   n0, n1, ew, eb, cnts, stg, cap);
    sortB<<<dim3(NRNG, 3), 1024, 0, stream>>>(stg, cap, rcur,
                                              n1, off0, edg0,
                                              n0, off1, edg1,
                                              n0, off2, edg2);

    const int nmax = (n0 > n1) ? n0 : n1;
    const int ebx = ((nmax + 1) / 2 + 3) / 4;
    edge_agg3<<<dim3(ebx, 3), blk, 0, stream>>>(
        off0, edg0, K0, Q1, V0, aggb1, n1,
        off1, edg1, K1, Q0, V1, aggb0a, n0,
        off2, edg2, K0, Q0, V0, aggb0b, n0);

    gemm_out<<<blocks0 + blocks1, blk, 0, stream>>>(aggb0a, aggb0b, aggb1, Wtbuf, Ab,
                                                    feat0, feat1, skip, (float*)d_out,
                                                    n0, n1, blocks0);
}

// Round 15
// 419.306 us; speedup vs baseline: 9.1824x; 1.0759x over previous
//
#include <hip/hip_runtime.h>
#include <hip/hip_bf16.h>
#include <hip/hip_fp16.h>
#include <math.h>

// HEAT layer. Round 15: (1) LDS-staged coalesced GEMM epilogues (kill per-lane
// 2B/4B scatter stores + scalar feat reads); (2) edge_agg3 2-edge ILP unroll
// (break serial z+=p chain). CSR pipeline unchanged from round 14.

#define NDIM 128
#define NRNG 32
#define NBK 512
#define UNITS (NBK * 4)
#define HSPAN 2048

typedef __attribute__((ext_vector_type(8))) short short8;
typedef __attribute__((ext_vector_type(4))) float f32x4;

__device__ __forceinline__ float bf2f(unsigned short u) {
    union { unsigned int i; float f; } x; x.i = ((unsigned int)u) << 16; return x.f;
}
__device__ __forceinline__ unsigned short f2bf(float f) {
    unsigned int u = __float_as_uint(f);
    unsigned int r = (u + 0x7FFFu + ((u >> 16) & 1u)) >> 16;   // RNE
    return (unsigned short)r;
}
__device__ __forceinline__ int range_of(int d, int n) {
    return (int)(((long long)d * NRNG) / n);
}

// ---------------- weight prep: 8 mats f32[k][n] -> bf16 [n][k] ----------------
__global__ void wt_prep(const float* __restrict__ Kw, const float* __restrict__ Qw,
                        const float* __restrict__ Vw, const float* __restrict__ Aw,
                        unsigned short* __restrict__ Wtbuf)
{
    const int b = blockIdx.x;        // t*4 + m
    const int t = b >> 2, m = b & 3;
    const float* src = (m == 0 ? Kw : m == 1 ? Qw : m == 2 ? Vw : Aw) + (size_t)t * 16384;
    unsigned short* dst = Wtbuf + (size_t)b * 16384;
    for (int i = threadIdx.x; i < 16384; i += blockDim.x) {
        const int k = i >> 7, nn = i & 127;
        dst[nn * 128 + k] = f2bf(src[i]);
    }
}

// ---------------- fused K/Q/V MFMA GEMM, LDS-staged epilogue ----------------
__global__ __launch_bounds__(256) void gemm_kqv(
    const float* __restrict__ feat0, const float* __restrict__ feat1,
    const unsigned short* __restrict__ Wtbuf,
    const float* __restrict__ Kb, const float* __restrict__ Qb, const float* __restrict__ Vb,
    unsigned short* __restrict__ K0o, unsigned short* __restrict__ Q0o, unsigned short* __restrict__ V0o,
    unsigned short* __restrict__ K1o, unsigned short* __restrict__ Q1o, unsigned short* __restrict__ V1o,
    int n0, int n1, int blocks0)
{
    const int b = blockIdx.x;
    const bool t1 = (b >= blocks0);
    const float* feat = t1 ? feat1 : feat0;
    const int n = t1 ? n1 : n0;
    const int boff = t1 ? NDIM : 0;
    const unsigned short* Wt = Wtbuf + (t1 ? 4 * 16384 : 0);
    unsigned short* outs[3];
    outs[0] = t1 ? K1o : K0o; outs[1] = t1 ? Q1o : Q0o; outs[2] = t1 ? V1o : V0o;
    const float* biases[3] = {Kb + boff, Qb + boff, Vb + boff};

    const int tid = threadIdx.x;
    const int w = tid >> 6, lane = tid & 63;
    const int r16 = lane & 15, kg = lane >> 4;
    const int brow = (t1 ? b - blocks0 : b) * 64;
    const int arow = min(brow + w * 16 + r16, n - 1);

    __shared__ float sacc[64][129];

    short8 afr[4];
#pragma unroll
    for (int k0i = 0; k0i < 4; ++k0i) {
        const float* ap = feat + (size_t)arow * NDIM + k0i * 32 + kg * 8;
        const float4 lo = *(const float4*)ap;
        const float4 hi = *(const float4*)(ap + 4);
        short8 a;
        a[0] = (short)f2bf(lo.x); a[1] = (short)f2bf(lo.y);
        a[2] = (short)f2bf(lo.z); a[3] = (short)f2bf(lo.w);
        a[4] = (short)f2bf(hi.x); a[5] = (short)f2bf(hi.y);
        a[6] = (short)f2bf(hi.z); a[7] = (short)f2bf(hi.w);
        afr[k0i] = a;
    }
    const int c8 = (lane & 15) * 8;
#pragma unroll
    for (int m = 0; m < 3; ++m) {
        const unsigned short* wt = Wt + (size_t)m * 16384;
        f32x4 acc[8];
#pragma unroll
        for (int c = 0; c < 8; ++c) acc[c] = (f32x4){0.f, 0.f, 0.f, 0.f};
#pragma unroll
        for (int k0i = 0; k0i < 4; ++k0i)
#pragma unroll
            for (int c = 0; c < 8; ++c) {
                const short8 bb = *(const short8*)(wt + (size_t)(16 * c + r16) * NDIM + k0i * 32 + kg * 8);
                acc[c] = __builtin_amdgcn_mfma_f32_16x16x32_bf16(afr[k0i], bb, acc[c], 0, 0, 0);
            }
        __syncthreads();
#pragma unroll
        for (int c = 0; c < 8; ++c)
#pragma unroll
            for (int j = 0; j < 4; ++j)
                sacc[w * 16 + kg * 4 + j][16 * c + r16] = acc[c][j];
        __syncthreads();
        const float4 blo = *(const float4*)(biases[m] + c8);
        const float4 bhi = *(const float4*)(biases[m] + c8 + 4);
        const float bias8[8] = {blo.x, blo.y, blo.z, blo.w, bhi.x, bhi.y, bhi.z, bhi.w};
#pragma unroll
        for (int j = 0; j < 4; ++j) {
            const int rloc = w * 16 + (lane >> 4) + j * 4;
            const int grow = brow + rloc;
            if (grow < n) {
                short8 o;
#pragma unroll
                for (int i = 0; i < 8; ++i)
                    o[i] = (short)f2bf(sacc[rloc][c8 + i] + bias8[i]);
                *(short8*)(outs[m] + (size_t)grow * NDIM + c8) = o;
            }
        }
    }
}

// ---------------- fused output MFMA GEMM, LDS-staged epilogue ----------------
__global__ __launch_bounds__(256) void gemm_out(
    const unsigned short* __restrict__ aggb0a, const unsigned short* __restrict__ aggb0b,
    const unsigned short* __restrict__ aggb1,
    const unsigned short* __restrict__ Wtbuf, const float* __restrict__ Ab,
    const float* __restrict__ feat0, const float* __restrict__ feat1,
    const float* __restrict__ skip, float* __restrict__ out,
    int n0, int n1, int blocks0)
{
    const int b = blockIdx.x;
    const bool t1 = (b >= blocks0);
    const int n = t1 ? n1 : n0;
    const unsigned short* A1 = t1 ? aggb1 : aggb0a;
    const unsigned short* A2 = t1 ? (const unsigned short*)nullptr : aggb0b;
    const unsigned short* Wt = Wtbuf + (t1 ? 7 : 3) * 16384;
    const float* bias = Ab + (t1 ? NDIM : 0);
    const float* feat = t1 ? feat1 : feat0;
    float* C = out + (t1 ? (size_t)n0 * NDIM : 0);
    const int nid = t1 ? 1 : 0;

    const int tid = threadIdx.x;
    const int w = tid >> 6, lane = tid & 63;
    const int r16 = lane & 15, kg = lane >> 4;
    const int brow = (t1 ? b - blocks0 : b) * 64;
    const int arow = min(brow + w * 16 + r16, n - 1);

    __shared__ float sacc[64][129];

    short8 afr[4];
#pragma unroll
    for (int k0i = 0; k0i < 4; ++k0i) {
        short8 a = *(const short8*)(A1 + (size_t)arow * NDIM + k0i * 32 + kg * 8);
        if (!t1) {
            const short8 bb = *(const short8*)(A2 + (size_t)arow * NDIM + k0i * 32 + kg * 8);
#pragma unroll
            for (int j = 0; j < 8; ++j) {
                const float v = 0.5f * (bf2f((unsigned short)a[j]) + bf2f((unsigned short)bb[j]));
                a[j] = (short)f2bf(v);
            }
        }
        afr[k0i] = a;
    }
    f32x4 acc[8];
#pragma unroll
    for (int c = 0; c < 8; ++c) acc[c] = (f32x4){0.f, 0.f, 0.f, 0.f};
#pragma unroll
    for (int k0i = 0; k0i < 4; ++k0i)
#pragma unroll
        for (int c = 0; c < 8; ++c) {
            const short8 bb = *(const short8*)(Wt + (size_t)(16 * c + r16) * NDIM + k0i * 32 + kg * 8);
            acc[c] = __builtin_amdgcn_mfma_f32_16x16x32_bf16(afr[k0i], bb, acc[c], 0, 0, 0);
        }
    __syncthreads();
#pragma unroll
    for (int c = 0; c < 8; ++c)
#pragma unroll
        for (int j = 0; j < 4; ++j)
            sacc[w * 16 + kg * 4 + j][16 * c + r16] = acc[c][j];
    __syncthreads();

    const float sk = skip[nid];
    const float alpha = 1.f / (1.f + __expf(-sk));
    const float beta = 1.f - alpha;
    const int c8 = (lane & 15) * 8;
    const float4 blo = *(const float4*)(bias + c8);
    const float4 bhi = *(const float4*)(bias + c8 + 4);
#pragma unroll
    for (int j = 0; j < 4; ++j) {
        const int rloc = w * 16 + (lane >> 4) + j * 4;
        const int grow = brow + rloc;
        if (grow < n) {
            const float4 fa = *(const float4*)(feat + (size_t)grow * NDIM + c8);
            const float4 fb = *(const float4*)(feat + (size_t)grow * NDIM + c8 + 4);
            float4 oa, ob;
            oa.x = (sacc[rloc][c8 + 0] + blo.x) * alpha + fa.x * beta;
            oa.y = (sacc[rloc][c8 + 1] + blo.y) * alpha + fa.y * beta;
            oa.z = (sacc[rloc][c8 + 2] + blo.z) * alpha + fa.z * beta;
            oa.w = (sacc[rloc][c8 + 3] + blo.w) * alpha + fa.w * beta;
            ob.x = (sacc[rloc][c8 + 4] + bhi.x) * alpha + fb.x * beta;
            ob.y = (sacc[rloc][c8 + 5] + bhi.y) * alpha + fb.y * beta;
            ob.z = (sacc[rloc][c8 + 6] + bhi.z) * alpha + fb.z * beta;
            ob.w = (sacc[rloc][c8 + 7] + bhi.w) * alpha + fb.w * beta;
            *(float4*)(C + (size_t)grow * NDIM + c8) = oa;
            *(float4*)(C + (size_t)grow * NDIM + c8 + 4) = ob;
        }
    }
}

// ---------------- phase A1: per-unit range counts ----------------
__global__ __launch_bounds__(256) void bucket_count(
    const int* __restrict__ d0, int E0, const int* __restrict__ d1, int E1,
    const int* __restrict__ d2, int E2, int n0, int n1, int* __restrict__ cnts)
{
    const int seg = blockIdx.y;
    const int* dst = seg == 0 ? d0 : (seg == 1 ? d1 : d2);
    const int E = seg == 0 ? E0 : (seg == 1 ? E1 : E2);
    const int ns = seg == 0 ? n1 : n0;
    const int unit = blockIdx.x * 4 + (threadIdx.x >> 6);
    const int lane = threadIdx.x & 63;
    const int span = (E + UNITS - 1) / UNITS;
    const int b = unit * span;
    const int e = min(b + span, E);

    int run[NRNG];
#pragma unroll
    for (int r0 = 0; r0 < NRNG; ++r0) run[r0] = 0;
    for (int i0 = b; i0 < e; i0 += 64) {
        const int i = i0 + lane;
        const bool v = i < e;
        const int d = v ? dst[i] : 0;
        const unsigned int r = v ? (unsigned int)range_of(d, ns) : 0xFFu;
#pragma unroll
        for (int r0 = 0; r0 < NRNG; ++r0)
            run[r0] += __popcll(__ballot(r == (unsigned int)r0));
    }
    if (lane == 0) {
        int* c = cnts + ((size_t)seg * UNITS + unit) * NRNG;
#pragma unroll
        for (int r0 = 0; r0 < NRNG; ++r0) c[r0] = run[r0];
    }
}

// ---------------- phase A2: exclusive scan of unit counts; totals -> rcur ----------------
__global__ __launch_bounds__(256) void bucket_scan(int* __restrict__ cnts, int* __restrict__ rcur)
{
    const int seg = blockIdx.x >> 5;
    const int r = blockIdx.x & 31;
    const int t = threadIdx.x, lane = t & 63, w = t >> 6;

    int v[8];
    int run = 0;
#pragma unroll
    for (int j = 0; j < 8; ++j) {
        const int u = t * 8 + j;
        const int x = cnts[((size_t)seg * UNITS + u) * NRNG + r];
        v[j] = run;
        run += x;
    }
    const int tsum = run;
    int x = tsum;
#pragma unroll
    for (int o = 1; o < 64; o <<= 1) {
        const int y = __shfl_up(x, o);
        if (lane >= o) x += y;
    }
    const int wexc = x - tsum;
    __shared__ int wsum[4];
    if (lane == 63) wsum[w] = x;
    __syncthreads();
    int wbase = 0;
    for (int i = 0; i < w; ++i) wbase += wsum[i];
    const int base = wbase + wexc;
#pragma unroll
    for (int j = 0; j < 8; ++j) {
        const int u = t * 8 + j;
        cnts[((size_t)seg * UNITS + u) * NRNG + r] = base + v[j];
    }
    if (t == 255) rcur[seg * NRNG + r] = base + tsum;
}

// ---------------- phase A3: deterministic staged write ----------------
__global__ __launch_bounds__(256) void bucket_write(
    const int* __restrict__ d0, const int* __restrict__ s0, const float* __restrict__ e0, int E0,
    const int* __restrict__ d1, const int* __restrict__ s1, const float* __restrict__ e1, int E1,
    const int* __restrict__ d2, const int* __restrict__ s2, const float* __restrict__ e2, int E2,
    int n0, int n1, const float* __restrict__ ew, const float* __restrict__ eb,
    const int* __restrict__ cnts, uint2* __restrict__ stg, int cap)
{
    const int seg = blockIdx.y;
    const int* dst = seg == 0 ? d0 : (seg == 1 ? d1 : d2);
    const int* src = seg == 0 ? s0 : (seg == 1 ? s1 : s2);
    const float* ev = seg == 0 ? e0 : (seg == 1 ? e1 : e2);
    const int E = seg == 0 ? E0 : (seg == 1 ? E1 : E2);
    const int ns = seg == 0 ? n1 : n0;
    const int unit = blockIdx.x * 4 + (threadIdx.x >> 6);
    const int lane = threadIdx.x & 63;
    const int span = (E + UNITS - 1) / UNITS;
    const int b = unit * span;
    const int e = min(b + span, E);
    const float LOG2E = 1.4426950408889634f;
    const float ews = ew[0] * 0.25f * LOG2E;
    const float ebs = eb[0] * 0.25f * LOG2E;
    uint2* sbase = stg + (size_t)seg * NRNG * cap;

    int run[NRNG];
    {
        const int* c = cnts + ((size_t)seg * UNITS + unit) * NRNG;
#pragma unroll
        for (int r0 = 0; r0 < NRNG; ++r0) run[r0] = c[r0];
    }
    for (int i0 = b; i0 < e; i0 += 64) {
        const int i = i0 + lane;
        const bool v = i < e;
        int d = 0, s = 0; float ee = 0.f;
        if (v) { d = dst[i]; s = src[i]; ee = ev[i]; }
        const unsigned int r = v ? (unsigned int)range_of(d, ns) : 0xFFu;
#pragma unroll
        for (int r0 = 0; r0 < NRNG; ++r0) {
            const unsigned long long m = __ballot(r == (unsigned int)r0);
            if (m == 0ull) continue;
            if (r == (unsigned int)r0) {
                const int off = run[r0] + __popcll(m & ((1ull << lane) - 1ull));
                sbase[(size_t)r0 * cap + off] =
                    make_uint2((unsigned int)d | ((unsigned int)s << 16), __float_as_uint(ee * ews + ebs));
            }
            run[r0] += __popcll(m);
        }
    }
}

// ---------------- phase B: per-range LDS counting sort -> off[] + edg[] (u32) ----------------
__global__ __launch_bounds__(1024) void sortB(
    const uint2* __restrict__ stg, int cap, const int* __restrict__ rcur,
    int nA, int* __restrict__ offA, unsigned int* __restrict__ gA,
    int nB, int* __restrict__ offB, unsigned int* __restrict__ gB,
    int nC, int* __restrict__ offC, unsigned int* __restrict__ gC)
{
    const int seg = blockIdx.y;
    const int r = blockIdx.x;
    const int n = seg == 0 ? nA : (seg == 1 ? nB : nC);
    int* off = seg == 0 ? offA : (seg == 1 ? offB : offC);
    unsigned int* edg = seg == 0 ? gA : (seg == 1 ? gB : gC);
    const int cnt = rcur[seg * NRNG + r];
    const uint2* s = stg + ((size_t)seg * NRNG + r) * cap;
    const int dbase = (int)(((long long)r * n + NRNG - 1) / NRNG);
    const int dnext = (int)(((long long)(r + 1) * n + NRNG - 1) / NRNG);
    const int span = dnext - dbase;
    int ebase = 0;
    for (int i = 0; i < r; ++i) ebase += rcur[seg * NRNG + i];

    __shared__ int hist[HSPAN];
    __shared__ int wsum[16];
    const int tid = threadIdx.x, lane = tid & 63, wid = tid >> 6;

    for (int i = tid; i < span; i += 1024) hist[i] = 0;
    __syncthreads();
    for (int i = tid; i < cnt; i += 1024)
        atomicAdd(&hist[(int)(s[i].x & 0xFFFFu) - dbase], 1);
    __syncthreads();
    const int C = (span + 1023) >> 10;
    int v[4];
    int run = 0;
    const int b0 = tid * C;
#pragma unroll 4
    for (int j = 0; j < C; ++j) {
        const int i = b0 + j;
        const int x = (i < span) ? hist[i] : 0;
        v[j] = run;
        run += x;
    }
    int x = run;
#pragma unroll
    for (int o = 1; o < 64; o <<= 1) {
        const int y = __shfl_up(x, o);
        if (lane >= o) x += y;
    }
    if (lane == 63) wsum[wid] = x;
    __syncthreads();
    int wbase = 0;
    for (int i = 0; i < wid; ++i) wbase += wsum[i];
    const int tb = ebase + wbase + (x - run);
#pragma unroll 4
    for (int j = 0; j < C; ++j) {
        const int i = b0 + j;
        if (i < span) hist[i] = tb + v[j];
    }
    __syncthreads();
    for (int i = tid; i < span; i += 1024) off[dbase + i] = hist[i];
    if (r == NRNG - 1 && tid == 0) off[n] = ebase + cnt;
    __syncthreads();
    for (int i = tid; i < cnt; i += 1024) {
        const uint2 e = s[i];
        const int d = (int)(e.x & 0xFFFFu);
        const int p = atomicAdd(&hist[d - dbase], 1);
        const float wf = __uint_as_float(e.y);
        const __half hh = __float2half(wf);
        edg[p] = (e.x >> 16) | ((unsigned int)__half_as_ushort(hh) << 16);
    }
}

// ---------------- edge aggregation v4: 2-edge ILP unroll ----------------
__global__ __launch_bounds__(256) void edge_agg3(
    const int* __restrict__ off0, const unsigned int* __restrict__ edg0,
    const unsigned short* __restrict__ K0e, const unsigned short* __restrict__ Q0e,
    const unsigned short* __restrict__ V0e, unsigned short* __restrict__ out0, int nd0,
    const int* __restrict__ off1, const unsigned int* __restrict__ edg1,
    const unsigned short* __restrict__ K1e, const unsigned short* __restrict__ Q1e,
    const unsigned short* __restrict__ V1e, unsigned short* __restrict__ out1, int nd1,
    const int* __restrict__ off2, const unsigned int* __restrict__ edg2,
    const unsigned short* __restrict__ K2e, const unsigned short* __restrict__ Q2e,
    const unsigned short* __restrict__ V2e, unsigned short* __restrict__ out2, int nd2)
{
    const int seg = blockIdx.y;
    const int* off = seg == 0 ? off0 : (seg == 1 ? off1 : off2);
    const unsigned int* edg = seg == 0 ? edg0 : (seg == 1 ? edg1 : edg2);
    const unsigned short* K = seg == 0 ? K0e : (seg == 1 ? K1e : K2e);
    const unsigned short* Q = seg == 0 ? Q0e : (seg == 1 ? Q1e : Q2e);
    const unsigned short* V = seg == 0 ? V0e : (seg == 1 ? V1e : V2e);
    unsigned short* aggb = seg == 0 ? out0 : (seg == 1 ? out1 : out2);
    const int n_dst = seg == 0 ? nd0 : (seg == 1 ? nd1 : nd2);

    const int wv = (blockIdx.x * blockDim.x + threadIdx.x) >> 6;
    const int lane = threadIdx.x & 63;
    const int half = lane >> 5, l5 = lane & 31;
    const int dst = 2 * wv + half;
    const bool valid = dst < n_dst;
    int beg = 0, len = 0;
    if (valid) { beg = off[dst]; len = off[dst + 1] - beg; }
    const int maxLen = max(len, __shfl_xor(len, 32));
    if (maxLen == 0) {
        if (valid) *(ushort4*)(aggb + (size_t)dst * NDIM + 4 * l5) = (ushort4){0, 0, 0, 0};
        return;
    }
    float qx = 0.f, qy = 0.f, qz = 0.f, qw = 0.f;
    if (valid) {
        const ushort4 qr = *(const ushort4*)(Q + (size_t)dst * NDIM + 4 * l5);
        qx = bf2f(qr.x); qy = bf2f(qr.y); qz = bf2f(qr.z); qw = bf2f(qr.w);
    }
    float zA = 0.f, aA0 = 0.f, aA1 = 0.f, aA2 = 0.f, aA3 = 0.f;
    float zB = 0.f, aB0 = 0.f, aB1 = 0.f, aB2 = 0.f, aB3 = 0.f;

    unsigned int ec = (l5 < len) ? edg[beg + l5] : 0u;
    for (int t0 = 0; t0 < maxLen; t0 += 32) {
        unsigned int en = 0u;
        const int t0n = t0 + 32;
        if (t0n < maxLen && t0n + l5 < len) en = edg[beg + t0n + l5];
        const int lim = min(32, maxLen - t0);
        for (int u = 0; u < lim; u += 2) {
            const int sl0 = (half << 5) + u;
            const unsigned int v0 = (unsigned int)__shfl((int)ec, sl0);
            const unsigned int v1 = (unsigned int)__shfl((int)ec, sl0 + 1);
            const bool act0 = (t0 + u) < len;
            const bool act1 = (u + 1 < lim) && ((t0 + u + 1) < len);
            const int s0 = (int)(v0 & 0xFFFFu);
            const int s1 = (int)(v1 & 0xFFFFu);
            const float w0 = __half2float(__ushort_as_half((unsigned short)(v0 >> 16)));
            const float w1 = __half2float(__ushort_as_half((unsigned short)(v1 >> 16)));
            const ushort4 kr0 = *(const ushort4*)(K + (size_t)s0 * NDIM + 4 * l5);
            const ushort4 vr0 = *(const ushort4*)(V + (size_t)s0 * NDIM + 4 * l5);
            const ushort4 kr1 = *(const ushort4*)(K + (size_t)s1 * NDIM + 4 * l5);
            const ushort4 vr1 = *(const ushort4*)(V + (size_t)s1 * NDIM + 4 * l5);
            float d0 = qx * bf2f(kr0.x) + qy * bf2f(kr0.y) + qz * bf2f(kr0.z) + qw * bf2f(kr0.w);
            float d1 = qx * bf2f(kr1.x) + qy * bf2f(kr1.y) + qz * bf2f(kr1.z) + qw * bf2f(kr1.w);
            d0 += __shfl_xor(d0, 1);
            d1 += __shfl_xor(d1, 1);
            d0 += __shfl_xor(d0, 2);
            d1 += __shfl_xor(d1, 2);
            const float p0 = act0 ? exp2f(d0 * w0) : 0.f;
            const float p1 = act1 ? exp2f(d1 * w1) : 0.f;
            zA += p0;
            aA0 += p0 * bf2f(vr0.x); aA1 += p0 * bf2f(vr0.y);
            aA2 += p0 * bf2f(vr0.z); aA3 += p0 * bf2f(vr0.w);
            zB += p1;
            aB0 += p1 * bf2f(vr1.x); aB1 += p1 * bf2f(vr1.y);
            aB2 += p1 * bf2f(vr1.z); aB3 += p1 * bf2f(vr1.w);
        }
        ec = en;
    }
    if (valid) {
        const float z = zA + zB;
        const float inv = (len > 0) ? 1.f / z : 0.f;
        ushort4 o;
        o.x = f2bf((aA0 + aB0) * inv); o.y = f2bf((aA1 + aB1) * inv);
        o.z = f2bf((aA2 + aB2) * inv); o.w = f2bf((aA3 + aB3) * inv);
        *(ushort4*)(aggb + (size_t)dst * NDIM + 4 * l5) = o;
    }
}

extern "C" void kernel_launch(void* const* d_in, const int* in_sizes, int n_in,
                              void* d_out, int out_size, void* d_ws, size_t ws_size,
                              hipStream_t stream)
{
    const float* feat0 = (const float*)d_in[0];
    const float* feat1 = (const float*)d_in[1];
    const float* ev0 = (const float*)d_in[2];
    const float* ev1 = (const float*)d_in[3];
    const float* ev2 = (const float*)d_in[4];
    const int* src0 = (const int*)d_in[5];
    const int* dst0 = (const int*)d_in[6];
    const int* src1 = (const int*)d_in[7];
    const int* dst1 = (const int*)d_in[8];
    const int* src2 = (const int*)d_in[9];
    const int* dst2 = (const int*)d_in[10];
    const float* Kw = (const float*)d_in[11];
    const float* Kb = (const float*)d_in[12];
    const float* Qw = (const float*)d_in[13];
    const float* Qb = (const float*)d_in[14];
    const float* Vw = (const float*)d_in[15];
    const float* Vb = (const float*)d_in[16];
    const float* Aw = (const float*)d_in[17];
    const float* Ab = (const float*)d_in[18];
    const float* ew = (const float*)d_in[19];
    const float* eb = (const float*)d_in[20];
    const float* skip = (const float*)d_in[21];

    const int n0 = in_sizes[0] / NDIM;
    const int n1 = in_sizes[1] / NDIM;
    const int E0 = in_sizes[5];
    const int E1 = in_sizes[7];
    const int E2 = in_sizes[9];
    if (max(n0, n1) > 65504) return;
    const int Emax = max(E0, max(E1, E2));
    const int cap = Emax / NRNG + 8192;

    auto rup = [](size_t b) { return (b + 255) & ~size_t(255); };
    const size_t need =
        rup((size_t)8 * 16384 * 2) +
        rup((size_t)n0 * NDIM * 2) * 3 +
        rup((size_t)n1 * NDIM * 2) * 3 +
        rup((size_t)n1 * NDIM * 2) +
        rup((size_t)n0 * NDIM * 2) * 2 +
        rup((size_t)(n1 + 1) * 4) +
        rup((size_t)(n0 + 1) * 4) * 2 +
        rup((size_t)128 * 4) +
        rup((size_t)3 * UNITS * NRNG * 4) +
        rup((size_t)3 * NRNG * cap * 8) +
        rup((size_t)E0 * 4) + rup((size_t)E1 * 4) + rup((size_t)E2 * 4);
    if (ws_size < need) return;

    char* p = (char*)d_ws;
    auto alloc = [&](size_t bytes) -> char* {
        char* r = p;
        p += (bytes + 255) & ~size_t(255);
        return r;
    };
    unsigned short* Wtbuf = (unsigned short*)alloc((size_t)8 * 16384 * 2);
    unsigned short* K0 = (unsigned short*)alloc((size_t)n0 * NDIM * 2);
    unsigned short* Q0 = (unsigned short*)alloc((size_t)n0 * NDIM * 2);
    unsigned short* V0 = (unsigned short*)alloc((size_t)n0 * NDIM * 2);
    unsigned short* K1 = (unsigned short*)alloc((size_t)n1 * NDIM * 2);
    unsigned short* Q1 = (unsigned short*)alloc((size_t)n1 * NDIM * 2);
    unsigned short* V1 = (unsigned short*)alloc((size_t)n1 * NDIM * 2);
    unsigned short* aggb1  = (unsigned short*)alloc((size_t)n1 * NDIM * 2);
    unsigned short* aggb0a = (unsigned short*)alloc((size_t)n0 * NDIM * 2);
    unsigned short* aggb0b = (unsigned short*)alloc((size_t)n0 * NDIM * 2);
    int* off0 = (int*)alloc((size_t)(n1 + 1) * 4);
    int* off1 = (int*)alloc((size_t)(n0 + 1) * 4);
    int* off2 = (int*)alloc((size_t)(n0 + 1) * 4);
    int* rcur = (int*)alloc((size_t)128 * 4);
    int* cnts = (int*)alloc((size_t)3 * UNITS * NRNG * 4);
    uint2* stg = (uint2*)alloc((size_t)3 * NRNG * cap * 8);
    unsigned int* edg0 = (unsigned int*)alloc((size_t)E0 * 4);
    unsigned int* edg1 = (unsigned int*)alloc((size_t)E1 * 4);
    unsigned int* edg2 = (unsigned int*)alloc((size_t)E2 * 4);

    dim3 blk(256);
    const int blocks0 = (n0 + 63) / 64, blocks1 = (n1 + 63) / 64;

    wt_prep<<<8, 256, 0, stream>>>(Kw, Qw, Vw, Aw, Wtbuf);
    gemm_kqv<<<blocks0 + blocks1, blk, 0, stream>>>(feat0, feat1, Wtbuf, Kb, Qb, Vb,
                                                    K0, Q0, V0, K1, Q1, V1, n0, n1, blocks0);

    bucket_count<<<dim3(NBK, 3), blk, 0, stream>>>(dst0, E0, dst1, E1, dst2, E2, n0, n1, cnts);
    bucket_scan<<<3 * NRNG, blk, 0, stream>>>(cnts, rcur);
    bucket_write<<<dim3(NBK, 3), blk, 0, stream>>>(dst0, src0, ev0, E0,
                                                   dst1, src1, ev1, E1,
                                                   dst2, src2, ev2, E2,
                                                   n0, n1, ew, eb, cnts, stg, cap);
    sortB<<<dim3(NRNG, 3), 1024, 0, stream>>>(stg, cap, rcur,
                                              n1, off0, edg0,
                                              n0, off1, edg1,
                                              n0, off2, edg2);

    const int nmax = (n0 > n1) ? n0 : n1;
    const int ebx = ((nmax + 1) / 2 + 3) / 4;
    edge_agg3<<<dim3(ebx, 3), blk, 0, stream>>>(
        off0, edg0, K0, Q1, V0, aggb1, n1,
        off1, edg1, K1, Q0, V1, aggb0a, n0,
        off2, edg2, K0, Q0, V0, aggb0b, n0);

    gemm_out<<<blocks0 + blocks1, blk, 0, stream>>>(aggb0a, aggb0b, aggb1, Wtbuf, Ab,
                                                    feat0, feat1, skip, (float*)d_out,
                                                    n0, n1, blocks0);
}

// Round 16
// 396.039 us; speedup vs baseline: 9.7219x; 1.0587x over previous
//
#include <hip/hip_runtime.h>
#include <hip/hip_bf16.h>
#include <hip/hip_fp16.h>
#include <math.h>

// HEAT layer. Round 16: (1) K/Q stored fp16 + fdot2 in edge_agg (VALU cut, V stays
// bf16); (2) wt_prep LDS transpose (was 2B-scalar-scatter on 8 CUs). Rest = r15.

#define NDIM 128
#define NRNG 32
#define NBK 512
#define UNITS (NBK * 4)
#define HSPAN 2048

typedef __attribute__((ext_vector_type(8))) short short8;
typedef __attribute__((ext_vector_type(4))) float f32x4;
typedef __attribute__((ext_vector_type(2))) _Float16 half2v;

__device__ __forceinline__ float bf2f(unsigned short u) {
    union { unsigned int i; float f; } x; x.i = ((unsigned int)u) << 16; return x.f;
}
__device__ __forceinline__ unsigned short f2bf(float f) {
    unsigned int u = __float_as_uint(f);
    unsigned int r = (u + 0x7FFFu + ((u >> 16) & 1u)) >> 16;   // RNE
    return (unsigned short)r;
}
__device__ __forceinline__ int range_of(int d, int n) {
    return (int)(((long long)d * NRNG) / n);
}
union U4h { ushort4 u; struct { half2v a, b; } h; };

// ---------------- weight prep: 8 mats f32[k][n] -> bf16 [n][k], LDS transpose ----------------
__global__ __launch_bounds__(256) void wt_prep(const float* __restrict__ Kw, const float* __restrict__ Qw,
                                               const float* __restrict__ Vw, const float* __restrict__ Aw,
                                               unsigned short* __restrict__ Wtbuf)
{
    const int b = blockIdx.x;        // t*4 + m
    const int t = b >> 2, m = b & 3;
    const float* src = (m == 0 ? Kw : m == 1 ? Qw : m == 2 ? Vw : Aw) + (size_t)t * 16384;
    unsigned short* dst = Wtbuf + (size_t)b * 16384;
    const int tid = threadIdx.x;
    __shared__ float tile[64][132];
#pragma unroll
    for (int h = 0; h < 2; ++h) {
        const int k0 = h * 64;
        for (int idx = tid; idx < 64 * 32; idx += 256) {
            const int kr = idx >> 5;
            const int c4 = (idx & 31) * 4;
            const float4 v = *(const float4*)(src + (size_t)(k0 + kr) * 128 + c4);
            tile[kr][c4 + 0] = v.x; tile[kr][c4 + 1] = v.y;
            tile[kr][c4 + 2] = v.z; tile[kr][c4 + 3] = v.w;
        }
        __syncthreads();
        for (int idx = tid; idx < 128 * 16; idx += 256) {
            const int nn = idx >> 4;
            const int kk4 = (idx & 15) * 4;
            ushort4 o;
            o.x = f2bf(tile[kk4 + 0][nn]); o.y = f2bf(tile[kk4 + 1][nn]);
            o.z = f2bf(tile[kk4 + 2][nn]); o.w = f2bf(tile[kk4 + 3][nn]);
            *(ushort4*)(dst + (size_t)nn * 128 + k0 + kk4) = o;
        }
        __syncthreads();
    }
}

// ---------------- fused K/Q/V MFMA GEMM (K,Q out fp16; V out bf16) ----------------
__global__ __launch_bounds__(256) void gemm_kqv(
    const float* __restrict__ feat0, const float* __restrict__ feat1,
    const unsigned short* __restrict__ Wtbuf,
    const float* __restrict__ Kb, const float* __restrict__ Qb, const float* __restrict__ Vb,
    unsigned short* __restrict__ K0o, unsigned short* __restrict__ Q0o, unsigned short* __restrict__ V0o,
    unsigned short* __restrict__ K1o, unsigned short* __restrict__ Q1o, unsigned short* __restrict__ V1o,
    int n0, int n1, int blocks0)
{
    const int b = blockIdx.x;
    const bool t1 = (b >= blocks0);
    const float* feat = t1 ? feat1 : feat0;
    const int n = t1 ? n1 : n0;
    const int boff = t1 ? NDIM : 0;
    const unsigned short* Wt = Wtbuf + (t1 ? 4 * 16384 : 0);
    unsigned short* outs[3];
    outs[0] = t1 ? K1o : K0o; outs[1] = t1 ? Q1o : Q0o; outs[2] = t1 ? V1o : V0o;
    const float* biases[3] = {Kb + boff, Qb + boff, Vb + boff};

    const int tid = threadIdx.x;
    const int w = tid >> 6, lane = tid & 63;
    const int r16 = lane & 15, kg = lane >> 4;
    const int brow = (t1 ? b - blocks0 : b) * 64;
    const int arow = min(brow + w * 16 + r16, n - 1);

    __shared__ float sacc[64][129];

    short8 afr[4];
#pragma unroll
    for (int k0i = 0; k0i < 4; ++k0i) {
        const float* ap = feat + (size_t)arow * NDIM + k0i * 32 + kg * 8;
        const float4 lo = *(const float4*)ap;
        const float4 hi = *(const float4*)(ap + 4);
        short8 a;
        a[0] = (short)f2bf(lo.x); a[1] = (short)f2bf(lo.y);
        a[2] = (short)f2bf(lo.z); a[3] = (short)f2bf(lo.w);
        a[4] = (short)f2bf(hi.x); a[5] = (short)f2bf(hi.y);
        a[6] = (short)f2bf(hi.z); a[7] = (short)f2bf(hi.w);
        afr[k0i] = a;
    }
    const int c8 = (lane & 15) * 8;
#pragma unroll
    for (int m = 0; m < 3; ++m) {
        const unsigned short* wt = Wt + (size_t)m * 16384;
        f32x4 acc[8];
#pragma unroll
        for (int c = 0; c < 8; ++c) acc[c] = (f32x4){0.f, 0.f, 0.f, 0.f};
#pragma unroll
        for (int k0i = 0; k0i < 4; ++k0i)
#pragma unroll
            for (int c = 0; c < 8; ++c) {
                const short8 bb = *(const short8*)(wt + (size_t)(16 * c + r16) * NDIM + k0i * 32 + kg * 8);
                acc[c] = __builtin_amdgcn_mfma_f32_16x16x32_bf16(afr[k0i], bb, acc[c], 0, 0, 0);
            }
        __syncthreads();
#pragma unroll
        for (int c = 0; c < 8; ++c)
#pragma unroll
            for (int j = 0; j < 4; ++j)
                sacc[w * 16 + kg * 4 + j][16 * c + r16] = acc[c][j];
        __syncthreads();
        const float4 blo = *(const float4*)(biases[m] + c8);
        const float4 bhi = *(const float4*)(biases[m] + c8 + 4);
        const float bias8[8] = {blo.x, blo.y, blo.z, blo.w, bhi.x, bhi.y, bhi.z, bhi.w};
#pragma unroll
        for (int j = 0; j < 4; ++j) {
            const int rloc = w * 16 + (lane >> 4) + j * 4;
            const int grow = brow + rloc;
            if (grow < n) {
                short8 o;
#pragma unroll
                for (int i = 0; i < 8; ++i) {
                    const float x = sacc[rloc][c8 + i] + bias8[i];
                    o[i] = (m < 2) ? (short)__half_as_ushort(__float2half(x))  // K,Q -> fp16
                                   : (short)f2bf(x);                           // V   -> bf16
                }
                *(short8*)(outs[m] + (size_t)grow * NDIM + c8) = o;
            }
        }
    }
}

// ---------------- fused output MFMA GEMM, LDS-staged epilogue ----------------
__global__ __launch_bounds__(256) void gemm_out(
    const unsigned short* __restrict__ aggb0a, const unsigned short* __restrict__ aggb0b,
    const unsigned short* __restrict__ aggb1,
    const unsigned short* __restrict__ Wtbuf, const float* __restrict__ Ab,
    const float* __restrict__ feat0, const float* __restrict__ feat1,
    const float* __restrict__ skip, float* __restrict__ out,
    int n0, int n1, int blocks0)
{
    const int b = blockIdx.x;
    const bool t1 = (b >= blocks0);
    const int n = t1 ? n1 : n0;
    const unsigned short* A1 = t1 ? aggb1 : aggb0a;
    const unsigned short* A2 = t1 ? (const unsigned short*)nullptr : aggb0b;
    const unsigned short* Wt = Wtbuf + (t1 ? 7 : 3) * 16384;
    const float* bias = Ab + (t1 ? NDIM : 0);
    const float* feat = t1 ? feat1 : feat0;
    float* C = out + (t1 ? (size_t)n0 * NDIM : 0);
    const int nid = t1 ? 1 : 0;

    const int tid = threadIdx.x;
    const int w = tid >> 6, lane = tid & 63;
    const int r16 = lane & 15, kg = lane >> 4;
    const int brow = (t1 ? b - blocks0 : b) * 64;
    const int arow = min(brow + w * 16 + r16, n - 1);

    __shared__ float sacc[64][129];

    short8 afr[4];
#pragma unroll
    for (int k0i = 0; k0i < 4; ++k0i) {
        short8 a = *(const short8*)(A1 + (size_t)arow * NDIM + k0i * 32 + kg * 8);
        if (!t1) {
            const short8 bb = *(const short8*)(A2 + (size_t)arow * NDIM + k0i * 32 + kg * 8);
#pragma unroll
            for (int j = 0; j < 8; ++j) {
                const float v = 0.5f * (bf2f((unsigned short)a[j]) + bf2f((unsigned short)bb[j]));
                a[j] = (short)f2bf(v);
            }
        }
        afr[k0i] = a;
    }
    f32x4 acc[8];
#pragma unroll
    for (int c = 0; c < 8; ++c) acc[c] = (f32x4){0.f, 0.f, 0.f, 0.f};
#pragma unroll
    for (int k0i = 0; k0i < 4; ++k0i)
#pragma unroll
        for (int c = 0; c < 8; ++c) {
            const short8 bb = *(const short8*)(Wt + (size_t)(16 * c + r16) * NDIM + k0i * 32 + kg * 8);
            acc[c] = __builtin_amdgcn_mfma_f32_16x16x32_bf16(afr[k0i], bb, acc[c], 0, 0, 0);
        }
    __syncthreads();
#pragma unroll
    for (int c = 0; c < 8; ++c)
#pragma unroll
        for (int j = 0; j < 4; ++j)
            sacc[w * 16 + kg * 4 + j][16 * c + r16] = acc[c][j];
    __syncthreads();

    const float sk = skip[nid];
    const float alpha = 1.f / (1.f + __expf(-sk));
    const float beta = 1.f - alpha;
    const int c8 = (lane & 15) * 8;
    const float4 blo = *(const float4*)(bias + c8);
    const float4 bhi = *(const float4*)(bias + c8 + 4);
#pragma unroll
    for (int j = 0; j < 4; ++j) {
        const int rloc = w * 16 + (lane >> 4) + j * 4;
        const int grow = brow + rloc;
        if (grow < n) {
            const float4 fa = *(const float4*)(feat + (size_t)grow * NDIM + c8);
            const float4 fb = *(const float4*)(feat + (size_t)grow * NDIM + c8 + 4);
            float4 oa, ob;
            oa.x = (sacc[rloc][c8 + 0] + blo.x) * alpha + fa.x * beta;
            oa.y = (sacc[rloc][c8 + 1] + blo.y) * alpha + fa.y * beta;
            oa.z = (sacc[rloc][c8 + 2] + blo.z) * alpha + fa.z * beta;
            oa.w = (sacc[rloc][c8 + 3] + blo.w) * alpha + fa.w * beta;
            ob.x = (sacc[rloc][c8 + 4] + bhi.x) * alpha + fb.x * beta;
            ob.y = (sacc[rloc][c8 + 5] + bhi.y) * alpha + fb.y * beta;
            ob.z = (sacc[rloc][c8 + 6] + bhi.z) * alpha + fb.z * beta;
            ob.w = (sacc[rloc][c8 + 7] + bhi.w) * alpha + fb.w * beta;
            *(float4*)(C + (size_t)grow * NDIM + c8) = oa;
            *(float4*)(C + (size_t)grow * NDIM + c8 + 4) = ob;
        }
    }
}

// ---------------- phase A1: per-unit range counts ----------------
__global__ __launch_bounds__(256) void bucket_count(
    const int* __restrict__ d0, int E0, const int* __restrict__ d1, int E1,
    const int* __restrict__ d2, int E2, int n0, int n1, int* __restrict__ cnts)
{
    const int seg = blockIdx.y;
    const int* dst = seg == 0 ? d0 : (seg == 1 ? d1 : d2);
    const int E = seg == 0 ? E0 : (seg == 1 ? E1 : E2);
    const int ns = seg == 0 ? n1 : n0;
    const int unit = blockIdx.x * 4 + (threadIdx.x >> 6);
    const int lane = threadIdx.x & 63;
    const int span = (E + UNITS - 1) / UNITS;
    const int b = unit * span;
    const int e = min(b + span, E);

    int run[NRNG];
#pragma unroll
    for (int r0 = 0; r0 < NRNG; ++r0) run[r0] = 0;
    for (int i0 = b; i0 < e; i0 += 64) {
        const int i = i0 + lane;
        const bool v = i < e;
        const int d = v ? dst[i] : 0;
        const unsigned int r = v ? (unsigned int)range_of(d, ns) : 0xFFu;
#pragma unroll
        for (int r0 = 0; r0 < NRNG; ++r0)
            run[r0] += __popcll(__ballot(r == (unsigned int)r0));
    }
    if (lane == 0) {
        int* c = cnts + ((size_t)seg * UNITS + unit) * NRNG;
#pragma unroll
        for (int r0 = 0; r0 < NRNG; ++r0) c[r0] = run[r0];
    }
}

// ---------------- phase A2: exclusive scan of unit counts; totals -> rcur ----------------
__global__ __launch_bounds__(256) void bucket_scan(int* __restrict__ cnts, int* __restrict__ rcur)
{
    const int seg = blockIdx.x >> 5;
    const int r = blockIdx.x & 31;
    const int t = threadIdx.x, lane = t & 63, w = t >> 6;

    int v[8];
    int run = 0;
#pragma unroll
    for (int j = 0; j < 8; ++j) {
        const int u = t * 8 + j;
        const int x = cnts[((size_t)seg * UNITS + u) * NRNG + r];
        v[j] = run;
        run += x;
    }
    const int tsum = run;
    int x = tsum;
#pragma unroll
    for (int o = 1; o < 64; o <<= 1) {
        const int y = __shfl_up(x, o);
        if (lane >= o) x += y;
    }
    const int wexc = x - tsum;
    __shared__ int wsum[4];
    if (lane == 63) wsum[w] = x;
    __syncthreads();
    int wbase = 0;
    for (int i = 0; i < w; ++i) wbase += wsum[i];
    const int base = wbase + wexc;
#pragma unroll
    for (int j = 0; j < 8; ++j) {
        const int u = t * 8 + j;
        cnts[((size_t)seg * UNITS + u) * NRNG + r] = base + v[j];
    }
    if (t == 255) rcur[seg * NRNG + r] = base + tsum;
}

// ---------------- phase A3: deterministic staged write ----------------
__global__ __launch_bounds__(256) void bucket_write(
    const int* __restrict__ d0, const int* __restrict__ s0, const float* __restrict__ e0, int E0,
    const int* __restrict__ d1, const int* __restrict__ s1, const float* __restrict__ e1, int E1,
    const int* __restrict__ d2, const int* __restrict__ s2, const float* __restrict__ e2, int E2,
    int n0, int n1, const float* __restrict__ ew, const float* __restrict__ eb,
    const int* __restrict__ cnts, uint2* __restrict__ stg, int cap)
{
    const int seg = blockIdx.y;
    const int* dst = seg == 0 ? d0 : (seg == 1 ? d1 : d2);
    const int* src = seg == 0 ? s0 : (seg == 1 ? s1 : s2);
    const float* ev = seg == 0 ? e0 : (seg == 1 ? e1 : e2);
    const int E = seg == 0 ? E0 : (seg == 1 ? E1 : E2);
    const int ns = seg == 0 ? n1 : n0;
    const int unit = blockIdx.x * 4 + (threadIdx.x >> 6);
    const int lane = threadIdx.x & 63;
    const int span = (E + UNITS - 1) / UNITS;
    const int b = unit * span;
    const int e = min(b + span, E);
    const float LOG2E = 1.4426950408889634f;
    const float ews = ew[0] * 0.25f * LOG2E;
    const float ebs = eb[0] * 0.25f * LOG2E;
    uint2* sbase = stg + (size_t)seg * NRNG * cap;

    int run[NRNG];
    {
        const int* c = cnts + ((size_t)seg * UNITS + unit) * NRNG;
#pragma unroll
        for (int r0 = 0; r0 < NRNG; ++r0) run[r0] = c[r0];
    }
    for (int i0 = b; i0 < e; i0 += 64) {
        const int i = i0 + lane;
        const bool v = i < e;
        int d = 0, s = 0; float ee = 0.f;
        if (v) { d = dst[i]; s = src[i]; ee = ev[i]; }
        const unsigned int r = v ? (unsigned int)range_of(d, ns) : 0xFFu;
#pragma unroll
        for (int r0 = 0; r0 < NRNG; ++r0) {
            const unsigned long long m = __ballot(r == (unsigned int)r0);
            if (m == 0ull) continue;
            if (r == (unsigned int)r0) {
                const int off = run[r0] + __popcll(m & ((1ull << lane) - 1ull));
                sbase[(size_t)r0 * cap + off] =
                    make_uint2((unsigned int)d | ((unsigned int)s << 16), __float_as_uint(ee * ews + ebs));
            }
            run[r0] += __popcll(m);
        }
    }
}

// ---------------- phase B: per-range LDS counting sort -> off[] + edg[] (u32) ----------------
__global__ __launch_bounds__(1024) void sortB(
    const uint2* __restrict__ stg, int cap, const int* __restrict__ rcur,
    int nA, int* __restrict__ offA, unsigned int* __restrict__ gA,
    int nB, int* __restrict__ offB, unsigned int* __restrict__ gB,
    int nC, int* __restrict__ offC, unsigned int* __restrict__ gC)
{
    const int seg = blockIdx.y;
    const int r = blockIdx.x;
    const int n = seg == 0 ? nA : (seg == 1 ? nB : nC);
    int* off = seg == 0 ? offA : (seg == 1 ? offB : offC);
    unsigned int* edg = seg == 0 ? gA : (seg == 1 ? gB : gC);
    const int cnt = rcur[seg * NRNG + r];
    const uint2* s = stg + ((size_t)seg * NRNG + r) * cap;
    const int dbase = (int)(((long long)r * n + NRNG - 1) / NRNG);
    const int dnext = (int)(((long long)(r + 1) * n + NRNG - 1) / NRNG);
    const int span = dnext - dbase;
    int ebase = 0;
    for (int i = 0; i < r; ++i) ebase += rcur[seg * NRNG + i];

    __shared__ int hist[HSPAN];
    __shared__ int wsum[16];
    const int tid = threadIdx.x, lane = tid & 63, wid = tid >> 6;

    for (int i = tid; i < span; i += 1024) hist[i] = 0;
    __syncthreads();
    for (int i = tid; i < cnt; i += 1024)
        atomicAdd(&hist[(int)(s[i].x & 0xFFFFu) - dbase], 1);
    __syncthreads();
    const int C = (span + 1023) >> 10;
    int v[4];
    int run = 0;
    const int b0 = tid * C;
#pragma unroll 4
    for (int j = 0; j < C; ++j) {
        const int i = b0 + j;
        const int x = (i < span) ? hist[i] : 0;
        v[j] = run;
        run += x;
    }
    int x = run;
#pragma unroll
    for (int o = 1; o < 64; o <<= 1) {
        const int y = __shfl_up(x, o);
        if (lane >= o) x += y;
    }
    if (lane == 63) wsum[wid] = x;
    __syncthreads();
    int wbase = 0;
    for (int i = 0; i < wid; ++i) wbase += wsum[i];
    const int tb = ebase + wbase + (x - run);
#pragma unroll 4
    for (int j = 0; j < C; ++j) {
        const int i = b0 + j;
        if (i < span) hist[i] = tb + v[j];
    }
    __syncthreads();
    for (int i = tid; i < span; i += 1024) off[dbase + i] = hist[i];
    if (r == NRNG - 1 && tid == 0) off[n] = ebase + cnt;
    __syncthreads();
    for (int i = tid; i < cnt; i += 1024) {
        const uint2 e = s[i];
        const int d = (int)(e.x & 0xFFFFu);
        const int p = atomicAdd(&hist[d - dbase], 1);
        const float wf = __uint_as_float(e.y);
        const __half hh = __float2half(wf);
        edg[p] = (e.x >> 16) | ((unsigned int)__half_as_ushort(hh) << 16);
    }
}

// ---------------- edge aggregation v5: fp16 K/Q + fdot2, 2-edge ILP ----------------
__global__ __launch_bounds__(256) void edge_agg3(
    const int* __restrict__ off0, const unsigned int* __restrict__ edg0,
    const unsigned short* __restrict__ K0e, const unsigned short* __restrict__ Q0e,
    const unsigned short* __restrict__ V0e, unsigned short* __restrict__ out0, int nd0,
    const int* __restrict__ off1, const unsigned int* __restrict__ edg1,
    const unsigned short* __restrict__ K1e, const unsigned short* __restrict__ Q1e,
    const unsigned short* __restrict__ V1e, unsigned short* __restrict__ out1, int nd1,
    const int* __restrict__ off2, const unsigned int* __restrict__ edg2,
    const unsigned short* __restrict__ K2e, const unsigned short* __restrict__ Q2e,
    const unsigned short* __restrict__ V2e, unsigned short* __restrict__ out2, int nd2)
{
    const int seg = blockIdx.y;
    const int* off = seg == 0 ? off0 : (seg == 1 ? off1 : off2);
    const unsigned int* edg = seg == 0 ? edg0 : (seg == 1 ? edg1 : edg2);
    const unsigned short* K = seg == 0 ? K0e : (seg == 1 ? K1e : K2e);
    const unsigned short* Q = seg == 0 ? Q0e : (seg == 1 ? Q1e : Q2e);
    const unsigned short* V = seg == 0 ? V0e : (seg == 1 ? V1e : V2e);
    unsigned short* aggb = seg == 0 ? out0 : (seg == 1 ? out1 : out2);
    const int n_dst = seg == 0 ? nd0 : (seg == 1 ? nd1 : nd2);

    const int wv = (blockIdx.x * blockDim.x + threadIdx.x) >> 6;
    const int lane = threadIdx.x & 63;
    const int half = lane >> 5, l5 = lane & 31;
    const int dst = 2 * wv + half;
    const bool valid = dst < n_dst;
    int beg = 0, len = 0;
    if (valid) { beg = off[dst]; len = off[dst + 1] - beg; }
    const int maxLen = max(len, __shfl_xor(len, 32));
    if (maxLen == 0) {
        if (valid) *(ushort4*)(aggb + (size_t)dst * NDIM + 4 * l5) = (ushort4){0, 0, 0, 0};
        return;
    }
    U4h q;
    q.u = make_ushort4(0, 0, 0, 0);
    if (valid) q.u = *(const ushort4*)(Q + (size_t)dst * NDIM + 4 * l5);
    const half2v q01 = q.h.a, q23 = q.h.b;

    float zA = 0.f, aA0 = 0.f, aA1 = 0.f, aA2 = 0.f, aA3 = 0.f;
    float zB = 0.f, aB0 = 0.f, aB1 = 0.f, aB2 = 0.f, aB3 = 0.f;

    unsigned int ec = (l5 < len) ? edg[beg + l5] : 0u;
    for (int t0 = 0; t0 < maxLen; t0 += 32) {
        unsigned int en = 0u;
        const int t0n = t0 + 32;
        if (t0n < maxLen && t0n + l5 < len) en = edg[beg + t0n + l5];
        const int lim = min(32, maxLen - t0);
        for (int u = 0; u < lim; u += 2) {
            const int sl0 = (half << 5) + u;
            const unsigned int v0 = (unsigned int)__shfl((int)ec, sl0);
            const unsigned int v1 = (unsigned int)__shfl((int)ec, sl0 + 1);
            const bool act0 = (t0 + u) < len;
            const bool act1 = (u + 1 < lim) && ((t0 + u + 1) < len);
            const int s0 = (int)(v0 & 0xFFFFu);
            const int s1 = (int)(v1 & 0xFFFFu);
            const float w0 = __half2float(__ushort_as_half((unsigned short)(v0 >> 16)));
            const float w1 = __half2float(__ushort_as_half((unsigned short)(v1 >> 16)));
            U4h k0u, k1u;
            k0u.u = *(const ushort4*)(K + (size_t)s0 * NDIM + 4 * l5);
            k1u.u = *(const ushort4*)(K + (size_t)s1 * NDIM + 4 * l5);
            const ushort4 vr0 = *(const ushort4*)(V + (size_t)s0 * NDIM + 4 * l5);
            const ushort4 vr1 = *(const ushort4*)(V + (size_t)s1 * NDIM + 4 * l5);
#if __has_builtin(__builtin_amdgcn_fdot2)
            float d0 = __builtin_amdgcn_fdot2(k0u.h.a, q01, 0.f, false);
            d0 = __builtin_amdgcn_fdot2(k0u.h.b, q23, d0, false);
            float d1 = __builtin_amdgcn_fdot2(k1u.h.a, q01, 0.f, false);
            d1 = __builtin_amdgcn_fdot2(k1u.h.b, q23, d1, false);
#else
            float d0 = (float)k0u.h.a[0] * (float)q01[0] + (float)k0u.h.a[1] * (float)q01[1]
                     + (float)k0u.h.b[0] * (float)q23[0] + (float)k0u.h.b[1] * (float)q23[1];
            float d1 = (float)k1u.h.a[0] * (float)q01[0] + (float)k1u.h.a[1] * (float)q01[1]
                     + (float)k1u.h.b[0] * (float)q23[0] + (float)k1u.h.b[1] * (float)q23[1];
#endif
            d0 += __shfl_xor(d0, 1);
            d1 += __shfl_xor(d1, 1);
            d0 += __shfl_xor(d0, 2);
            d1 += __shfl_xor(d1, 2);
            const float p0 = act0 ? exp2f(d0 * w0) : 0.f;
            const float p1 = act1 ? exp2f(d1 * w1) : 0.f;
            zA += p0;
            aA0 += p0 * bf2f(vr0.x); aA1 += p0 * bf2f(vr0.y);
            aA2 += p0 * bf2f(vr0.z); aA3 += p0 * bf2f(vr0.w);
            zB += p1;
            aB0 += p1 * bf2f(vr1.x); aB1 += p1 * bf2f(vr1.y);
            aB2 += p1 * bf2f(vr1.z); aB3 += p1 * bf2f(vr1.w);
        }
        ec = en;
    }
    if (valid) {
        const float z = zA + zB;
        const float inv = (len > 0) ? 1.f / z : 0.f;
        ushort4 o;
        o.x = f2bf((aA0 + aB0) * inv); o.y = f2bf((aA1 + aB1) * inv);
        o.z = f2bf((aA2 + aB2) * inv); o.w = f2bf((aA3 + aB3) * inv);
        *(ushort4*)(aggb + (size_t)dst * NDIM + 4 * l5) = o;
    }
}

extern "C" void kernel_launch(void* const* d_in, const int* in_sizes, int n_in,
                              void* d_out, int out_size, void* d_ws, size_t ws_size,
                              hipStream_t stream)
{
    const float* feat0 = (const float*)d_in[0];
    const float* feat1 = (const float*)d_in[1];
    const float* ev0 = (const float*)d_in[2];
    const float* ev1 = (const float*)d_in[3];
    const float* ev2 = (const float*)d_in[4];
    const int* src0 = (const int*)d_in[5];
    const int* dst0 = (const int*)d_in[6];
    const int* src1 = (const int*)d_in[7];
    const int* dst1 = (const int*)d_in[8];
    const int* src2 = (const int*)d_in[9];
    const int* dst2 = (const int*)d_in[10];
    const float* Kw = (const float*)d_in[11];
    const float* Kb = (const float*)d_in[12];
    const float* Qw = (const float*)d_in[13];
    const float* Qb = (const float*)d_in[14];
    const float* Vw = (const float*)d_in[15];
    const float* Vb = (const float*)d_in[16];
    const float* Aw = (const float*)d_in[17];
    const float* Ab = (const float*)d_in[18];
    const float* ew = (const float*)d_in[19];
    const float* eb = (const float*)d_in[20];
    const float* skip = (const float*)d_in[21];

    const int n0 = in_sizes[0] / NDIM;
    const int n1 = in_sizes[1] / NDIM;
    const int E0 = in_sizes[5];
    const int E1 = in_sizes[7];
    const int E2 = in_sizes[9];
    if (max(n0, n1) > 65504) return;
    const int Emax = max(E0, max(E1, E2));
    const int cap = Emax / NRNG + 8192;

    auto rup = [](size_t b) { return (b + 255) & ~size_t(255); };
    const size_t need =
        rup((size_t)8 * 16384 * 2) +
        rup((size_t)n0 * NDIM * 2) * 3 +
        rup((size_t)n1 * NDIM * 2) * 3 +
        rup((size_t)n1 * NDIM * 2) +
        rup((size_t)n0 * NDIM * 2) * 2 +
        rup((size_t)(n1 + 1) * 4) +
        rup((size_t)(n0 + 1) * 4) * 2 +
        rup((size_t)128 * 4) +
        rup((size_t)3 * UNITS * NRNG * 4) +
        rup((size_t)3 * NRNG * cap * 8) +
        rup((size_t)E0 * 4) + rup((size_t)E1 * 4) + rup((size_t)E2 * 4);
    if (ws_size < need) return;

    char* p = (char*)d_ws;
    auto alloc = [&](size_t bytes) -> char* {
        char* r = p;
        p += (bytes + 255) & ~size_t(255);
        return r;
    };
    unsigned short* Wtbuf = (unsigned short*)alloc((size_t)8 * 16384 * 2);
    unsigned short* K0 = (unsigned short*)alloc((size_t)n0 * NDIM * 2);
    unsigned short* Q0 = (unsigned short*)alloc((size_t)n0 * NDIM * 2);
    unsigned short* V0 = (unsigned short*)alloc((size_t)n0 * NDIM * 2);
    unsigned short* K1 = (unsigned short*)alloc((size_t)n1 * NDIM * 2);
    unsigned short* Q1 = (unsigned short*)alloc((size_t)n1 * NDIM * 2);
    unsigned short* V1 = (unsigned short*)alloc((size_t)n1 * NDIM * 2);
    unsigned short* aggb1  = (unsigned short*)alloc((size_t)n1 * NDIM * 2);
    unsigned short* aggb0a = (unsigned short*)alloc((size_t)n0 * NDIM * 2);
    unsigned short* aggb0b = (unsigned short*)alloc((size_t)n0 * NDIM * 2);
    int* off0 = (int*)alloc((size_t)(n1 + 1) * 4);
    int* off1 = (int*)alloc((size_t)(n0 + 1) * 4);
    int* off2 = (int*)alloc((size_t)(n0 + 1) * 4);
    int* rcur = (int*)alloc((size_t)128 * 4);
    int* cnts = (int*)alloc((size_t)3 * UNITS * NRNG * 4);
    uint2* stg = (uint2*)alloc((size_t)3 * NRNG * cap * 8);
    unsigned int* edg0 = (unsigned int*)alloc((size_t)E0 * 4);
    unsigned int* edg1 = (unsigned int*)alloc((size_t)E1 * 4);
    unsigned int* edg2 = (unsigned int*)alloc((size_t)E2 * 4);

    dim3 blk(256);
    const int blocks0 = (n0 + 63) / 64, blocks1 = (n1 + 63) / 64;

    wt_prep<<<8, 256, 0, stream>>>(Kw, Qw, Vw, Aw, Wtbuf);
    gemm_kqv<<<blocks0 + blocks1, blk, 0, stream>>>(feat0, feat1, Wtbuf, Kb, Qb, Vb,
                                                    K0, Q0, V0, K1, Q1, V1, n0, n1, blocks0);

    bucket_count<<<dim3(NBK, 3), blk, 0, stream>>>(dst0, E0, dst1, E1, dst2, E2, n0, n1, cnts);
    bucket_scan<<<3 * NRNG, blk, 0, stream>>>(cnts, rcur);
    bucket_write<<<dim3(NBK, 3), blk, 0, stream>>>(dst0, src0, ev0, E0,
                                                   dst1, src1, ev1, E1,
                                                   dst2, src2, ev2, E2,
                                                   n0, n1, ew, eb, cnts, stg, cap);
    sortB<<<dim3(NRNG, 3), 1024, 0, stream>>>(stg, cap, rcur,
                                              n1, off0, edg0,
                                              n0, off1, edg1,
                                              n0, off2, edg2);

    const int nmax = (n0 > n1) ? n0 : n1;
    const int ebx = ((nmax + 1) / 2 + 3) / 4;
    edge_agg3<<<dim3(ebx, 3), blk, 0, stream>>>(
        off0, edg0, K0, Q1, V0, aggb1, n1,
        off1, edg1, K1, Q0, V1, aggb0a, n0,
        off2, edg2, K0, Q0, V0, aggb0b, n0);

    gemm_out<<<blocks0 + blocks1, blk, 0, stream>>>(aggb0a, aggb0b, aggb1, Wtbuf, Ab,
                                                    feat0, feat1, skip, (float*)d_out,
                                                    n0, n1, blocks0);
}